// Round 4
// baseline (221.000 us; speedup 1.0000x reference)
//
#include <hip/hip_runtime.h>

#define SEQ  2048
#define DH   64
#define QBLK 128         // q rows per block = 4 waves x 2 subtiles x 16
#define KBLK 64          // k/v rows per staged tile
#define NQB  (SEQ/QBLK)  // 16
#define THR  11.5f       // defer-max threshold, log2 domain (~e^8)

typedef short bf16x8 __attribute__((ext_vector_type(8)));   // 8 bf16 bits = 4 VGPRs
typedef float f32x4  __attribute__((ext_vector_type(4)));

// fp32 -> bf16 bits, round-to-nearest-even
__device__ __forceinline__ short bfbits(float f) {
    unsigned int u = __float_as_uint(f);
    u += 0x7fff + ((u >> 16) & 1);
    return (short)(u >> 16);
}

// swizzled short-index into a [rows][64] bf16 LDS tile (row stride 128 B):
// XOR bits 3..5 of elem idx (bits 4..6 of byte addr) with row bits 0..2.
__device__ __forceinline__ int swz(int row, int col) {
    return row * 64 + (col ^ ((row & 7) << 3));
}

// prefetch next K/V tile rows into registers (issued early; latency hides under compute)
#define LOAD_STAGE(kb_) do {                                               \
    const float* ksrc = Kb + (size_t)((kb_) + skr) * DH + sd0;             \
    kr0 = *reinterpret_cast<const float4*>(ksrc);                          \
    kr1 = *reinterpret_cast<const float4*>(ksrc + 4);                      \
    kr2 = *reinterpret_cast<const float4*>(ksrc + 8);                      \
    kr3 = *reinterpret_cast<const float4*>(ksrc + 12);                     \
    const float* vsrc = Vb + (size_t)((kb_) + svk) * DH + svd0;            \
    vr0 = *reinterpret_cast<const float4*>(vsrc);                          \
    vr1 = *reinterpret_cast<const float4*>(vsrc + 4);                      \
    vr2 = *reinterpret_cast<const float4*>(vsrc + 8);                      \
    vr3 = *reinterpret_cast<const float4*>(vsrc + 12);                     \
} while (0)

__global__ __launch_bounds__(256) void attn_fwd(const float* __restrict__ Qg,
                                                const float* __restrict__ Kg,
                                                const float* __restrict__ Vg,
                                                float* __restrict__ Og) {
    __shared__ __align__(16) short Ks[64 * 64];      // K tile [k][d], swizzled
    __shared__ __align__(16) short Vt[64 * 64];      // V tile [d][k], swizzled
    __shared__ __align__(16) short Ps[4 * 16 * 64];  // per-wave P [q][k], swizzled

    const int tid  = threadIdx.x;
    const int w    = tid >> 6;
    const int lane = tid & 63;
    const int lg   = lane >> 4;
    const int lr   = lane & 15;

    // longest-first: high qblk (most K-tiles) dispatched first
    const int qblk = (NQB - 1) - (blockIdx.x & (NQB - 1));
    const int bh   = blockIdx.x / NQB;
    const int q0   = qblk * QBLK;

    const float* Qb = Qg + (size_t)bh * SEQ * DH;
    const float* Kb = Kg + (size_t)bh * SEQ * DH;
    const float* Vb = Vg + (size_t)bh * SEQ * DH;
    float*       Ob = Og + (size_t)bh * SEQ * DH;

    // 1/sqrt(64) * log2(e): exp2-direct softmax
    const float SC = 0.125f * 1.44269504f;

    // staging thread mapping
    const int skr  = tid >> 2;          // K: row in tile
    const int sd0  = (tid & 3) * 16;    // K: 16-f32 col group
    const int svk  = tid & 63;          // V: k row
    const int svd0 = (tid >> 6) * 16;   // V: 16-f32 d group

    float4 kr0, kr1, kr2, kr3, vr0, vr1, vr2, vr3;   // stage registers
    LOAD_STAGE(0);                                    // prologue: tile 0 in flight

    // ---- Q fragments for both subtiles (A-layout: row=lane&15, chunk=(lane>>4)*8) ----
    bf16x8 qf[2][2];
    #pragma unroll
    for (int sub = 0; sub < 2; ++sub) {
        const float* qp = Qb + (size_t)(q0 + sub * 64 + w * 16 + lr) * DH + lg * 8;
        #pragma unroll
        for (int c = 0; c < 2; ++c) {
            const float4 a = *reinterpret_cast<const float4*>(qp + c * 32);
            const float4 b = *reinterpret_cast<const float4*>(qp + c * 32 + 4);
            bf16x8 r;
            r[0] = bfbits(a.x * SC); r[1] = bfbits(a.y * SC);
            r[2] = bfbits(a.z * SC); r[3] = bfbits(a.w * SC);
            r[4] = bfbits(b.x * SC); r[5] = bfbits(b.y * SC);
            r[6] = bfbits(b.z * SC); r[7] = bfbits(b.w * SC);
            qf[sub][c] = r;
        }
    }

    f32x4 o[2][4];
    float m_r[2][4], l_r[2][4];
    #pragma unroll
    for (int sub = 0; sub < 2; ++sub) {
        #pragma unroll
        for (int dt = 0; dt < 4; ++dt) o[sub][dt] = (f32x4){0.f, 0.f, 0.f, 0.f};
        #pragma unroll
        for (int r = 0; r < 4; ++r) { m_r[sub][r] = -1e30f; l_r[sub][r] = 0.f; }
    }

    const int kend0 = q0 + w * 16 + 16;       // subtile 0 causal limit
    const int kend1 = q0 + 64 + w * 16 + 16;  // subtile 1 causal limit
    const int kb_max = q0 + QBLK;

    for (int kb = 0; kb < kb_max; kb += KBLK) {
        __syncthreads();   // previous tile's LDS consumers done

        // ---- write staged tile t (regs -> cvt -> swizzled LDS) ----
        {
            bf16x8 h0, h1;
            h0[0]=bfbits(kr0.x); h0[1]=bfbits(kr0.y); h0[2]=bfbits(kr0.z); h0[3]=bfbits(kr0.w);
            h0[4]=bfbits(kr1.x); h0[5]=bfbits(kr1.y); h0[6]=bfbits(kr1.z); h0[7]=bfbits(kr1.w);
            h1[0]=bfbits(kr2.x); h1[1]=bfbits(kr2.y); h1[2]=bfbits(kr2.z); h1[3]=bfbits(kr2.w);
            h1[4]=bfbits(kr3.x); h1[5]=bfbits(kr3.y); h1[6]=bfbits(kr3.z); h1[7]=bfbits(kr3.w);
            *reinterpret_cast<bf16x8*>(&Ks[swz(skr, sd0)])     = h0;
            *reinterpret_cast<bf16x8*>(&Ks[swz(skr, sd0 + 8)]) = h1;

            const float vv[16] = {vr0.x,vr0.y,vr0.z,vr0.w, vr1.x,vr1.y,vr1.z,vr1.w,
                                  vr2.x,vr2.y,vr2.z,vr2.w, vr3.x,vr3.y,vr3.z,vr3.w};
            #pragma unroll
            for (int i = 0; i < 16; ++i)
                Vt[swz(svd0 + i, svk)] = bfbits(vv[i]);
        }

        // ---- issue next tile's global loads (latency hides under compute below) ----
        if (kb + KBLK < kb_max) LOAD_STAGE(kb + KBLK);

        __syncthreads();   // tile t ready in LDS

        // K fragments shared by both subtiles (held in regs)
        bf16x8 kf[4][2];
        #pragma unroll
        for (int kt = 0; kt < 4; ++kt)
            #pragma unroll
            for (int c = 0; c < 2; ++c)
                kf[kt][c] = *reinterpret_cast<const bf16x8*>(&Ks[swz(kt * 16 + lr, c * 32 + lg * 8)]);

        #pragma unroll
        for (int sub = 0; sub < 2; ++sub) {
            const int kend = sub ? kend1 : kend0;
            if (kb < kend) {
                const int qbase = q0 + sub * 64 + w * 16;

                // ---- S = Q K^T ----
                f32x4 s[4];
                #pragma unroll
                for (int kt = 0; kt < 4; ++kt) {
                    s[kt] = (f32x4){0.f, 0.f, 0.f, 0.f};
                    s[kt] = __builtin_amdgcn_mfma_f32_16x16x32_bf16(qf[sub][0], kf[kt][0], s[kt], 0, 0, 0);
                    s[kt] = __builtin_amdgcn_mfma_f32_16x16x32_bf16(qf[sub][1], kf[kt][1], s[kt], 0, 0, 0);
                }

                // ---- causal mask (boundary tiles only) ----
                #pragma unroll
                for (int kt = 0; kt < 4; ++kt) {
                    const int c0 = kb + kt * 16;
                    if (c0 + 15 > qbase) {
                        #pragma unroll
                        for (int r = 0; r < 4; ++r)
                            if (c0 + lr > qbase + lg * 4 + r) s[kt][r] = -1e30f;
                    }
                }

                // ---- in-lane max + defer-max fast path ----
                float mxl[4];
                int fastok = 1;
                #pragma unroll
                for (int r = 0; r < 4; ++r) {
                    mxl[r] = fmaxf(fmaxf(s[0][r], s[1][r]), fmaxf(s[2][r], s[3][r]));
                    fastok &= (mxl[r] <= m_r[sub][r] + THR);
                }
                if (!__all(fastok)) {       // slow path: true row max + rescale
                    #pragma unroll
                    for (int d = 1; d < 16; d <<= 1)
                        #pragma unroll
                        for (int r = 0; r < 4; ++r)
                            mxl[r] = fmaxf(mxl[r], __shfl_xor(mxl[r], d));
                    float scl[4];
                    #pragma unroll
                    for (int r = 0; r < 4; ++r) {
                        const float mn = fmaxf(m_r[sub][r], mxl[r]);
                        scl[r] = __builtin_amdgcn_exp2f(m_r[sub][r] - mn);
                        m_r[sub][r] = mn;
                        l_r[sub][r] *= scl[r];
                    }
                    #pragma unroll
                    for (int dt = 0; dt < 4; ++dt)
                        #pragma unroll
                        for (int r = 0; r < 4; ++r)
                            o[sub][dt][r] *= scl[r];
                }

                // ---- P = exp2(S - m), lane-partial row sum ----
                float p[4][4];
                #pragma unroll
                for (int kt = 0; kt < 4; ++kt)
                    #pragma unroll
                    for (int r = 0; r < 4; ++r)
                        p[kt][r] = __builtin_amdgcn_exp2f(s[kt][r] - m_r[sub][r]);
                #pragma unroll
                for (int r = 0; r < 4; ++r)
                    l_r[sub][r] += (p[0][r] + p[1][r]) + (p[2][r] + p[3][r]);

                // ---- P -> swizzled LDS (wave-private) ----
                const int pb = w * 1024;
                #pragma unroll
                for (int kt = 0; kt < 4; ++kt)
                    #pragma unroll
                    for (int r = 0; r < 4; ++r)
                        Ps[pb + swz(lg * 4 + r, kt * 16 + lr)] = bfbits(p[kt][r]);

                // ---- V and P fragments ----
                bf16x8 vf[4][2];
                #pragma unroll
                for (int dt = 0; dt < 4; ++dt)
                    #pragma unroll
                    for (int ks = 0; ks < 2; ++ks)
                        vf[dt][ks] = *reinterpret_cast<const bf16x8*>(&Vt[swz(dt * 16 + lr, ks * 32 + lg * 8)]);
                bf16x8 pa[2];
                #pragma unroll
                for (int ks = 0; ks < 2; ++ks)
                    pa[ks] = *reinterpret_cast<const bf16x8*>(&Ps[pb + swz(lr, ks * 32 + lg * 8)]);

                // ---- O += P V ----
                #pragma unroll
                for (int dt = 0; dt < 4; ++dt) {
                    o[sub][dt] = __builtin_amdgcn_mfma_f32_16x16x32_bf16(pa[0], vf[dt][0], o[sub][dt], 0, 0, 0);
                    o[sub][dt] = __builtin_amdgcn_mfma_f32_16x16x32_bf16(pa[1], vf[dt][1], o[sub][dt], 0, 0, 0);
                }
            }
        }
    }

    // ---- epilogue: reduce lane-partial l across 16 lanes, store ----
    #pragma unroll
    for (int sub = 0; sub < 2; ++sub) {
        #pragma unroll
        for (int d = 1; d < 16; d <<= 1)
            #pragma unroll
            for (int r = 0; r < 4; ++r)
                l_r[sub][r] += __shfl_xor(l_r[sub][r], d);
        #pragma unroll
        for (int r = 0; r < 4; ++r) {
            const float inv = 1.0f / l_r[sub][r];
            const int qg = q0 + sub * 64 + w * 16 + lg * 4 + r;
            #pragma unroll
            for (int dt = 0; dt < 4; ++dt)
                Ob[(size_t)qg * DH + dt * 16 + lr] = o[sub][dt][r] * inv;
        }
    }
}

extern "C" void kernel_launch(void* const* d_in, const int* in_sizes, int n_in,
                              void* d_out, int out_size, void* d_ws, size_t ws_size,
                              hipStream_t stream) {
    const float* Q = (const float*)d_in[0];
    const float* K = (const float*)d_in[1];
    const float* V = (const float*)d_in[2];
    // d_in[3] causal mask: synthesized in-kernel, not read.
    float* O = (float*)d_out;

    dim3 grid(64 * NQB);   // (B*H) * (S/QBLK) = 1024 blocks
    attn_fwd<<<grid, 256, 0, stream>>>(Q, K, V, O);
}

// Round 5
// 179.669 us; speedup vs baseline: 1.2300x; 1.2300x over previous
//
#include <hip/hip_runtime.h>

#define SEQ  2048
#define DH   64
#define QBLK 128         // 4 waves x 32 q-rows
#define KBLK 64          // k/v rows per staged tile
#define NQB  (SEQ/QBLK)  // 16
#define THR  11.5f       // defer-max threshold (log2 domain)
#define KPAT(r) ((((r)&3)) + 8*((r)>>2))   // 32x32 C/D row pattern

typedef short bf16x8 __attribute__((ext_vector_type(8)));   // 8 bf16 bits = 4 VGPRs
typedef float f32x16 __attribute__((ext_vector_type(16)));

union V4U { unsigned int w[4]; bf16x8 v; };

// fp32 -> bf16 bits, round-to-nearest-even (scalar; used for V scatter only)
__device__ __forceinline__ short bfbits(float f) {
    unsigned int u = __float_as_uint(f);
    u += 0x7fff + ((u >> 16) & 1);
    return (short)(u >> 16);
}
// packed 2xfp32 -> 2xbf16 in one VALU op
__device__ __forceinline__ unsigned int cvtpk(float lo, float hi) {
    unsigned int r;
    asm("v_cvt_pk_bf16_f32 %0, %1, %2" : "=v"(r) : "v"(lo), "v"(hi));
    return r;
}
// swizzled short-index into a [rows][64] bf16 LDS tile (row stride 128 B)
__device__ __forceinline__ int swz(int row, int col) {
    return row * 64 + (col ^ ((row & 7) << 3));
}

__global__ __launch_bounds__(256) void attn_fwd(const float* __restrict__ Qg,
                                                const float* __restrict__ Kg,
                                                const float* __restrict__ Vg,
                                                float* __restrict__ Og) {
    __shared__ __align__(16) short Ks[64 * 64];   // K tile [k][d], swizzled
    __shared__ __align__(16) short Vt[64 * 64];   // V tile [d][k], swizzled

    const int tid  = threadIdx.x;
    const int w    = tid >> 6;
    const int lane = tid & 63;
    const int h    = lane >> 5;      // half-wave (k-chunk selector)
    const int ql   = lane & 31;      // lane's q-col (S^T) / d-col (O)

    const int qblk = blockIdx.x & (NQB - 1);
    const int bh   = blockIdx.x / NQB;
    const int q0   = qblk * QBLK;
    const int qw   = q0 + w * 32;    // wave's 32 q-rows
    const int q    = qw + ql;        // lane's softmax row

    const float* Qb = Qg + (size_t)bh * SEQ * DH;
    const float* Kb = Kg + (size_t)bh * SEQ * DH;
    const float* Vb = Vg + (size_t)bh * SEQ * DH;
    float*       Ob = Og + (size_t)bh * SEQ * DH;

    const float SC = 0.125f * 1.44269504f;   // 1/sqrt(64) * log2(e)

    // ---- Q B-frags (col=lane&31=q, k-chunk d = dc*16 + h*8 + j) ----
    bf16x8 qb[4];
    {
        const float* qp = Qb + (size_t)q * DH + h * 8;
        #pragma unroll
        for (int dc = 0; dc < 4; ++dc) {
            const float4 a = *reinterpret_cast<const float4*>(qp + dc * 16);
            const float4 b = *reinterpret_cast<const float4*>(qp + dc * 16 + 4);
            V4U u;
            u.w[0] = cvtpk(a.x * SC, a.y * SC);
            u.w[1] = cvtpk(a.z * SC, a.w * SC);
            u.w[2] = cvtpk(b.x * SC, b.y * SC);
            u.w[3] = cvtpk(b.z * SC, b.w * SC);
            qb[dc] = u.v;
        }
    }

    f32x16 o0, o1;                          // O[q-rows][d=ql] and [d=32+ql]
    #pragma unroll
    for (int i = 0; i < 16; ++i) { o0[i] = 0.f; o1[i] = 0.f; }
    float m = -1e30f, lsum = 0.f;           // per-lane (q-row) state; lsum is half-row partial

    // staging thread mapping (same as R3)
    const int skr  = tid >> 2;
    const int sd0  = (tid & 3) * 16;
    const int svk  = tid & 63;
    const int svd0 = (tid >> 6) * 16;

    const int kend   = qw + 32;             // wave's causal k limit (exclusive)
    const int kb_max = q0 + QBLK;

    for (int kb = 0; kb < kb_max; kb += KBLK) {
        __syncthreads();
        // ---- stage K tile (cvt_pk packed, b128 writes) ----
        {
            const float* src = Kb + (size_t)(kb + skr) * DH + sd0;
            const float4 a0 = *reinterpret_cast<const float4*>(src);
            const float4 a1 = *reinterpret_cast<const float4*>(src + 4);
            const float4 a2 = *reinterpret_cast<const float4*>(src + 8);
            const float4 a3 = *reinterpret_cast<const float4*>(src + 12);
            V4U u0, u1;
            u0.w[0] = cvtpk(a0.x, a0.y); u0.w[1] = cvtpk(a0.z, a0.w);
            u0.w[2] = cvtpk(a1.x, a1.y); u0.w[3] = cvtpk(a1.z, a1.w);
            u1.w[0] = cvtpk(a2.x, a2.y); u1.w[1] = cvtpk(a2.z, a2.w);
            u1.w[2] = cvtpk(a3.x, a3.y); u1.w[3] = cvtpk(a3.z, a3.w);
            *reinterpret_cast<bf16x8*>(&Ks[swz(skr, sd0)])     = u0.v;
            *reinterpret_cast<bf16x8*>(&Ks[swz(skr, sd0 + 8)]) = u1.v;
        }
        // ---- stage V transposed (u16 scatter; row-uniform per write => conflict-free) ----
        {
            const float* src = Vb + (size_t)(kb + svk) * DH + svd0;
            const float4 b0 = *reinterpret_cast<const float4*>(src);
            const float4 b1 = *reinterpret_cast<const float4*>(src + 4);
            const float4 b2 = *reinterpret_cast<const float4*>(src + 8);
            const float4 b3 = *reinterpret_cast<const float4*>(src + 12);
            const float vv[16] = {b0.x,b0.y,b0.z,b0.w, b1.x,b1.y,b1.z,b1.w,
                                  b2.x,b2.y,b2.z,b2.w, b3.x,b3.y,b3.z,b3.w};
            #pragma unroll
            for (int i = 0; i < 16; ++i)
                Vt[swz(svd0 + i, svk)] = bfbits(vv[i]);
        }
        __syncthreads();

        if (kb >= kend) continue;           // wave-uniform causal skip (barriers at loop top)
        const bool v2 = (kb + 32 < kend);   // second 32-k sub-block live?

        // ---- S^T = K Q^T : lane owns q-col ql; rows k = kb + sb*32 + KPAT(r) + 4h ----
        f32x16 sT0, sT1;
        #pragma unroll
        for (int i = 0; i < 16; ++i) sT0[i] = 0.f;
        #pragma unroll
        for (int dc = 0; dc < 4; ++dc) {
            const bf16x8 ka = *reinterpret_cast<const bf16x8*>(&Ks[swz(ql, dc * 16 + h * 8)]);
            sT0 = __builtin_amdgcn_mfma_f32_32x32x16_bf16(ka, qb[dc], sT0, 0, 0, 0);
        }
        if (v2) {
            #pragma unroll
            for (int i = 0; i < 16; ++i) sT1[i] = 0.f;
            #pragma unroll
            for (int dc = 0; dc < 4; ++dc) {
                const bf16x8 ka = *reinterpret_cast<const bf16x8*>(&Ks[swz(32 + ql, dc * 16 + h * 8)]);
                sT1 = __builtin_amdgcn_mfma_f32_32x32x16_bf16(ka, qb[dc], sT1, 0, 0, 0);
            }
        }

        // ---- causal mask (boundary sub-blocks only; q fixed per lane) ----
        if (kb + 31 > qw) {
            #pragma unroll
            for (int r = 0; r < 16; ++r)
                if (kb + KPAT(r) + 4 * h > q) sT0[r] = -1e30f;
        }
        if (v2 && (kb + 63 > qw)) {
            #pragma unroll
            for (int r = 0; r < 16; ++r)
                if (kb + 32 + KPAT(r) + 4 * h > q) sT1[r] = -1e30f;
        }

        // ---- in-lane max + defer-max fast path ----
        float mx = sT0[0];
        #pragma unroll
        for (int r = 1; r < 16; ++r) mx = fmaxf(mx, sT0[r]);
        if (v2) {
            #pragma unroll
            for (int r = 0; r < 16; ++r) mx = fmaxf(mx, sT1[r]);
        }
        if (!__all(mx <= m + THR)) {        // slow path: full row max + O/l rescale
            mx = fmaxf(mx, __shfl_xor(mx, 32));
            const float mn  = fmaxf(m, mx);
            const float scl = __builtin_amdgcn_exp2f(m - mn);
            m = mn;
            lsum *= scl;
            #pragma unroll
            for (int r = 0; r < 16; ++r) {   // redistribute q-indexed scl to O-row layout
                const float sr = __shfl(scl, KPAT(r) + 4 * h);
                o0[r] *= sr; o1[r] *= sr;
            }
        }

        // ---- P = exp2(S^T - m), lane-partial l, pack + half-exchange into A-frags ----
        bf16x8 pa[4];
        {
            float p0[16];
            #pragma unroll
            for (int r = 0; r < 16; ++r) p0[r] = __builtin_amdgcn_exp2f(sT0[r] - m);
            #pragma unroll
            for (int r = 0; r < 16; ++r) lsum += p0[r];
            #pragma unroll
            for (int oct = 0; oct < 2; ++oct) {
                const unsigned int A0 = cvtpk(p0[oct*8+0], p0[oct*8+1]);
                const unsigned int A1 = cvtpk(p0[oct*8+2], p0[oct*8+3]);
                const unsigned int B0 = cvtpk(p0[oct*8+4], p0[oct*8+5]);
                const unsigned int B1 = cvtpk(p0[oct*8+6], p0[oct*8+7]);
                const unsigned int s0 = h ? A0 : B0, s1 = h ? A1 : B1;
                const unsigned int r0 = (unsigned int)__shfl_xor((int)s0, 32);
                const unsigned int r1 = (unsigned int)__shfl_xor((int)s1, 32);
                V4U u;
                u.w[0] = h ? r0 : A0; u.w[1] = h ? r1 : A1;
                u.w[2] = h ? B0 : r0; u.w[3] = h ? B1 : r1;
                pa[oct] = u.v;
            }
        }
        if (v2) {
            float p1[16];
            #pragma unroll
            for (int r = 0; r < 16; ++r) p1[r] = __builtin_amdgcn_exp2f(sT1[r] - m);
            #pragma unroll
            for (int r = 0; r < 16; ++r) lsum += p1[r];
            #pragma unroll
            for (int oct = 0; oct < 2; ++oct) {
                const unsigned int A0 = cvtpk(p1[oct*8+0], p1[oct*8+1]);
                const unsigned int A1 = cvtpk(p1[oct*8+2], p1[oct*8+3]);
                const unsigned int B0 = cvtpk(p1[oct*8+4], p1[oct*8+5]);
                const unsigned int B1 = cvtpk(p1[oct*8+6], p1[oct*8+7]);
                const unsigned int s0 = h ? A0 : B0, s1 = h ? A1 : B1;
                const unsigned int r0 = (unsigned int)__shfl_xor((int)s0, 32);
                const unsigned int r1 = (unsigned int)__shfl_xor((int)s1, 32);
                V4U u;
                u.w[0] = h ? r0 : A0; u.w[1] = h ? r1 : A1;
                u.w[2] = h ? B0 : r0; u.w[3] = h ? B1 : r1;
                pa[2 + oct] = u.v;
            }
        }

        // ---- O += P V  (B-frags from transposed V tile) ----
        #pragma unroll
        for (int kt = 0; kt < 2; ++kt) {
            const bf16x8 vb0 = *reinterpret_cast<const bf16x8*>(&Vt[swz(ql,      kt * 16 + h * 8)]);
            const bf16x8 vb1 = *reinterpret_cast<const bf16x8*>(&Vt[swz(32 + ql, kt * 16 + h * 8)]);
            o0 = __builtin_amdgcn_mfma_f32_32x32x16_bf16(pa[kt], vb0, o0, 0, 0, 0);
            o1 = __builtin_amdgcn_mfma_f32_32x32x16_bf16(pa[kt], vb1, o1, 0, 0, 0);
        }
        if (v2) {
            #pragma unroll
            for (int kt = 2; kt < 4; ++kt) {
                const bf16x8 vb0 = *reinterpret_cast<const bf16x8*>(&Vt[swz(ql,      kt * 16 + h * 8)]);
                const bf16x8 vb1 = *reinterpret_cast<const bf16x8*>(&Vt[swz(32 + ql, kt * 16 + h * 8)]);
                o0 = __builtin_amdgcn_mfma_f32_32x32x16_bf16(pa[kt], vb0, o0, 0, 0, 0);
                o1 = __builtin_amdgcn_mfma_f32_32x32x16_bf16(pa[kt], vb1, o1, 0, 0, 0);
            }
        }
    }

    // ---- epilogue: combine half-row sums, redistribute 1/l, store ----
    lsum += __shfl_xor(lsum, 32);
    const float inv = 1.0f / lsum;
    #pragma unroll
    for (int r = 0; r < 16; ++r) {
        const float ir  = __shfl(inv, KPAT(r) + 4 * h);
        const size_t row = (size_t)(qw + KPAT(r) + 4 * h);
        Ob[row * DH + ql]      = o0[r] * ir;
        Ob[row * DH + 32 + ql] = o1[r] * ir;
    }
}

extern "C" void kernel_launch(void* const* d_in, const int* in_sizes, int n_in,
                              void* d_out, int out_size, void* d_ws, size_t ws_size,
                              hipStream_t stream) {
    const float* Q = (const float*)d_in[0];
    const float* K = (const float*)d_in[1];
    const float* V = (const float*)d_in[2];
    // d_in[3] causal mask: synthesized in-kernel, not read.
    float* O = (float*)d_out;

    dim3 grid(64 * NQB);   // (B*H) * (S/QBLK) = 1024 blocks
    attn_fwd<<<grid, 256, 0, stream>>>(Q, K, V, O);
}

// Round 6
// 145.272 us; speedup vs baseline: 1.5213x; 1.2368x over previous
//
#include <hip/hip_runtime.h>

#define SEQ  2048
#define DH   64
#define QBLK 128         // 4 waves x 32 q-rows
#define KBLK 64          // k/v rows per staged tile
#define NQB  (SEQ/QBLK)  // 16
#define THR  11.5f       // defer-max threshold (log2 domain)
#define KPAT(r) ((((r)&3)) + 8*((r)>>2))   // 32x32 C/D row pattern

typedef short bf16x8 __attribute__((ext_vector_type(8)));   // 8 bf16 bits = 4 VGPRs
typedef float f32x16 __attribute__((ext_vector_type(16)));

union V4U { unsigned int w[4]; bf16x8 v; };

// fp32 -> bf16 bits, round-to-nearest-even (V scatter only)
__device__ __forceinline__ short bfbits(float f) {
    unsigned int u = __float_as_uint(f);
    u += 0x7fff + ((u >> 16) & 1);
    return (short)(u >> 16);
}
// packed 2xfp32 -> 2xbf16 in one VALU op
__device__ __forceinline__ unsigned int cvtpk(float lo, float hi) {
    unsigned int r;
    asm("v_cvt_pk_bf16_f32 %0, %1, %2" : "=v"(r) : "v"(lo), "v"(hi));
    return r;
}
// swizzled short-index into a [rows][64] bf16 LDS tile (row stride 128 B)
__device__ __forceinline__ int swz(int row, int col) {
    return row * 64 + (col ^ ((row & 7) << 3));
}

// issue next tile's global loads into registers (latency hides under compute)
#define LOAD_STAGE(kb_) do {                                               \
    const float* ksrc = Kb + (size_t)((kb_) + skr) * DH + sd0;             \
    kr0 = *reinterpret_cast<const float4*>(ksrc);                          \
    kr1 = *reinterpret_cast<const float4*>(ksrc + 4);                      \
    kr2 = *reinterpret_cast<const float4*>(ksrc + 8);                      \
    kr3 = *reinterpret_cast<const float4*>(ksrc + 12);                     \
    const float* vsrc = Vb + (size_t)((kb_) + svk) * DH + svd0;            \
    vr0 = *reinterpret_cast<const float4*>(vsrc);                          \
    vr1 = *reinterpret_cast<const float4*>(vsrc + 4);                      \
    vr2 = *reinterpret_cast<const float4*>(vsrc + 8);                      \
    vr3 = *reinterpret_cast<const float4*>(vsrc + 12);                     \
} while (0)

// cvt staged regs -> bf16 -> swizzled LDS buffer b (consumes the loads => free vmcnt at barrier)
#define CVT_WRITE(b_) do {                                                 \
    V4U u0, u1;                                                            \
    u0.w[0] = cvtpk(kr0.x, kr0.y); u0.w[1] = cvtpk(kr0.z, kr0.w);          \
    u0.w[2] = cvtpk(kr1.x, kr1.y); u0.w[3] = cvtpk(kr1.z, kr1.w);          \
    u1.w[0] = cvtpk(kr2.x, kr2.y); u1.w[1] = cvtpk(kr2.z, kr2.w);          \
    u1.w[2] = cvtpk(kr3.x, kr3.y); u1.w[3] = cvtpk(kr3.z, kr3.w);          \
    *reinterpret_cast<bf16x8*>(&Ks[b_][swz(skr, sd0)])     = u0.v;         \
    *reinterpret_cast<bf16x8*>(&Ks[b_][swz(skr, sd0 + 8)]) = u1.v;         \
    const float vv[16] = {vr0.x,vr0.y,vr0.z,vr0.w, vr1.x,vr1.y,vr1.z,vr1.w,\
                          vr2.x,vr2.y,vr2.z,vr2.w, vr3.x,vr3.y,vr3.z,vr3.w};\
    _Pragma("unroll")                                                      \
    for (int i_ = 0; i_ < 16; ++i_)                                        \
        Vt[b_][swz(svd0 + i_, svk)] = bfbits(vv[i_]);                      \
} while (0)

__global__ __launch_bounds__(256) void attn_fwd(const float* __restrict__ Qg,
                                                const float* __restrict__ Kg,
                                                const float* __restrict__ Vg,
                                                float* __restrict__ Og) {
    __shared__ __align__(16) short Ks[2][64 * 64];   // K tiles [k][d], swizzled, dbuf
    __shared__ __align__(16) short Vt[2][64 * 64];   // V tiles [d][k], swizzled, dbuf

    const int tid  = threadIdx.x;
    const int w    = tid >> 6;
    const int lane = tid & 63;
    const int h    = lane >> 5;      // half-wave (k-chunk selector)
    const int ql   = lane & 31;      // lane's q-col (S^T) / d-col (O)

    const int qblk = blockIdx.x & (NQB - 1);
    const int bh   = blockIdx.x / NQB;
    const int q0   = qblk * QBLK;
    const int qw   = q0 + w * 32;    // wave's 32 q-rows
    const int q    = qw + ql;        // lane's softmax row

    const float* Qb = Qg + (size_t)bh * SEQ * DH;
    const float* Kb = Kg + (size_t)bh * SEQ * DH;
    const float* Vb = Vg + (size_t)bh * SEQ * DH;
    float*       Ob = Og + (size_t)bh * SEQ * DH;

    const float SC = 0.125f * 1.44269504f;   // 1/sqrt(64) * log2(e)

    // staging thread mapping
    const int skr  = tid >> 2;
    const int sd0  = (tid & 3) * 16;
    const int svk  = tid & 63;
    const int svd0 = (tid >> 6) * 16;

    float4 kr0, kr1, kr2, kr3, vr0, vr1, vr2, vr3;
    LOAD_STAGE(0);                   // tile 0 in flight; Q conversion hides it

    // ---- Q B-frags (col=lane&31=q, k-chunk d = dc*16 + h*8 + j) ----
    bf16x8 qb[4];
    {
        const float* qp = Qb + (size_t)q * DH + h * 8;
        #pragma unroll
        for (int dc = 0; dc < 4; ++dc) {
            const float4 a = *reinterpret_cast<const float4*>(qp + dc * 16);
            const float4 b = *reinterpret_cast<const float4*>(qp + dc * 16 + 4);
            V4U u;
            u.w[0] = cvtpk(a.x * SC, a.y * SC);
            u.w[1] = cvtpk(a.z * SC, a.w * SC);
            u.w[2] = cvtpk(b.x * SC, b.y * SC);
            u.w[3] = cvtpk(b.z * SC, b.w * SC);
            qb[dc] = u.v;
        }
    }

    f32x16 o0, o1;                   // O[q-rows][d=ql] and [d=32+ql]
    #pragma unroll
    for (int i = 0; i < 16; ++i) { o0[i] = 0.f; o1[i] = 0.f; }
    float m = -1e30f, lsum = 0.f;    // per-lane (q-row) state; lsum is half-row partial

    CVT_WRITE(0);
    __syncthreads();                 // buf0 ready

    const int kend = qw + 32;              // wave's causal k limit (exclusive)
    const int nt   = (q0 + QBLK) / KBLK;   // tiles this block needs

    for (int t = 0; t < nt; ++t) {
        const int kb  = t * KBLK;
        const int cur = t & 1;
        if (t + 1 < nt) LOAD_STAGE(kb + KBLK);   // issue early: hides under compute

        if (kb < kend) {             // wave-uniform causal skip
            const bool v2 = (kb + 32 < kend);

            // ---- S^T = K Q^T : lane owns q-col ql; rows k = kb + sb*32 + KPAT(r) + 4h ----
            f32x16 sT0, sT1;
            #pragma unroll
            for (int i = 0; i < 16; ++i) sT0[i] = 0.f;
            #pragma unroll
            for (int dc = 0; dc < 4; ++dc) {
                const bf16x8 ka = *reinterpret_cast<const bf16x8*>(&Ks[cur][swz(ql, dc * 16 + h * 8)]);
                sT0 = __builtin_amdgcn_mfma_f32_32x32x16_bf16(ka, qb[dc], sT0, 0, 0, 0);
            }
            if (v2) {
                #pragma unroll
                for (int i = 0; i < 16; ++i) sT1[i] = 0.f;
                #pragma unroll
                for (int dc = 0; dc < 4; ++dc) {
                    const bf16x8 ka = *reinterpret_cast<const bf16x8*>(&Ks[cur][swz(32 + ql, dc * 16 + h * 8)]);
                    sT1 = __builtin_amdgcn_mfma_f32_32x32x16_bf16(ka, qb[dc], sT1, 0, 0, 0);
                }
            }

            // ---- causal mask (boundary sub-blocks only) ----
            if (kb + 31 > qw) {
                #pragma unroll
                for (int r = 0; r < 16; ++r)
                    if (kb + KPAT(r) + 4 * h > q) sT0[r] = -1e30f;
            }
            if (v2 && (kb + 63 > qw)) {
                #pragma unroll
                for (int r = 0; r < 16; ++r)
                    if (kb + 32 + KPAT(r) + 4 * h > q) sT1[r] = -1e30f;
            }

            // ---- in-lane max + defer-max fast path ----
            float mx = sT0[0];
            #pragma unroll
            for (int r = 1; r < 16; ++r) mx = fmaxf(mx, sT0[r]);
            if (v2) {
                #pragma unroll
                for (int r = 0; r < 16; ++r) mx = fmaxf(mx, sT1[r]);
            }
            if (!__all(mx <= m + THR)) {     // slow path: full row max + O/l rescale
                mx = fmaxf(mx, __shfl_xor(mx, 32));
                const float mn  = fmaxf(m, mx);
                const float scl = __builtin_amdgcn_exp2f(m - mn);
                m = mn;
                lsum *= scl;
                #pragma unroll
                for (int r = 0; r < 16; ++r) {
                    const float sr = __shfl(scl, KPAT(r) + 4 * h);
                    o0[r] *= sr; o1[r] *= sr;
                }
            }

            // ---- P = exp2(S^T - m), lane-partial l, pack + half-exchange into A-frags ----
            bf16x8 pa[4];
            {
                float p0[16];
                #pragma unroll
                for (int r = 0; r < 16; ++r) p0[r] = __builtin_amdgcn_exp2f(sT0[r] - m);
                #pragma unroll
                for (int r = 0; r < 16; ++r) lsum += p0[r];
                #pragma unroll
                for (int oct = 0; oct < 2; ++oct) {
                    const unsigned int A0 = cvtpk(p0[oct*8+0], p0[oct*8+1]);
                    const unsigned int A1 = cvtpk(p0[oct*8+2], p0[oct*8+3]);
                    const unsigned int B0 = cvtpk(p0[oct*8+4], p0[oct*8+5]);
                    const unsigned int B1 = cvtpk(p0[oct*8+6], p0[oct*8+7]);
                    const unsigned int s0 = h ? A0 : B0, s1 = h ? A1 : B1;
                    const unsigned int r0 = (unsigned int)__shfl_xor((int)s0, 32);
                    const unsigned int r1 = (unsigned int)__shfl_xor((int)s1, 32);
                    V4U u;
                    u.w[0] = h ? r0 : A0; u.w[1] = h ? r1 : A1;
                    u.w[2] = h ? B0 : r0; u.w[3] = h ? B1 : r1;
                    pa[oct] = u.v;
                }
            }
            if (v2) {
                float p1[16];
                #pragma unroll
                for (int r = 0; r < 16; ++r) p1[r] = __builtin_amdgcn_exp2f(sT1[r] - m);
                #pragma unroll
                for (int r = 0; r < 16; ++r) lsum += p1[r];
                #pragma unroll
                for (int oct = 0; oct < 2; ++oct) {
                    const unsigned int A0 = cvtpk(p1[oct*8+0], p1[oct*8+1]);
                    const unsigned int A1 = cvtpk(p1[oct*8+2], p1[oct*8+3]);
                    const unsigned int B0 = cvtpk(p1[oct*8+4], p1[oct*8+5]);
                    const unsigned int B1 = cvtpk(p1[oct*8+6], p1[oct*8+7]);
                    const unsigned int s0 = h ? A0 : B0, s1 = h ? A1 : B1;
                    const unsigned int r0 = (unsigned int)__shfl_xor((int)s0, 32);
                    const unsigned int r1 = (unsigned int)__shfl_xor((int)s1, 32);
                    V4U u;
                    u.w[0] = h ? r0 : A0; u.w[1] = h ? r1 : A1;
                    u.w[2] = h ? B0 : r0; u.w[3] = h ? B1 : r1;
                    pa[2 + oct] = u.v;
                }
            }

            // ---- O += P V  (B-frags from transposed V tile) ----
            #pragma unroll
            for (int kt = 0; kt < 2; ++kt) {
                const bf16x8 vb0 = *reinterpret_cast<const bf16x8*>(&Vt[cur][swz(ql,      kt * 16 + h * 8)]);
                const bf16x8 vb1 = *reinterpret_cast<const bf16x8*>(&Vt[cur][swz(32 + ql, kt * 16 + h * 8)]);
                o0 = __builtin_amdgcn_mfma_f32_32x32x16_bf16(pa[kt], vb0, o0, 0, 0, 0);
                o1 = __builtin_amdgcn_mfma_f32_32x32x16_bf16(pa[kt], vb1, o1, 0, 0, 0);
            }
            if (v2) {
                #pragma unroll
                for (int kt = 2; kt < 4; ++kt) {
                    const bf16x8 vb0 = *reinterpret_cast<const bf16x8*>(&Vt[cur][swz(ql,      kt * 16 + h * 8)]);
                    const bf16x8 vb1 = *reinterpret_cast<const bf16x8*>(&Vt[cur][swz(32 + ql, kt * 16 + h * 8)]);
                    o0 = __builtin_amdgcn_mfma_f32_32x32x16_bf16(pa[kt], vb0, o0, 0, 0, 0);
                    o1 = __builtin_amdgcn_mfma_f32_32x32x16_bf16(pa[kt], vb1, o1, 0, 0, 0);
                }
            }
        }

        // ---- write next tile (consumes the in-flight loads BEFORE the barrier,
        //      so the compiler's vmcnt(0)-at-barrier drain is free) ----
        if (t + 1 < nt) CVT_WRITE(cur ^ 1);
        __syncthreads();
    }

    // ---- epilogue: combine half-row sums, redistribute 1/l, store ----
    lsum += __shfl_xor(lsum, 32);
    const float inv = 1.0f / lsum;
    #pragma unroll
    for (int r = 0; r < 16; ++r) {
        const float ir  = __shfl(inv, KPAT(r) + 4 * h);
        const size_t row = (size_t)(qw + KPAT(r) + 4 * h);
        Ob[row * DH + ql]      = o0[r] * ir;
        Ob[row * DH + 32 + ql] = o1[r] * ir;
    }
}

extern "C" void kernel_launch(void* const* d_in, const int* in_sizes, int n_in,
                              void* d_out, int out_size, void* d_ws, size_t ws_size,
                              hipStream_t stream) {
    const float* Q = (const float*)d_in[0];
    const float* K = (const float*)d_in[1];
    const float* V = (const float*)d_in[2];
    // d_in[3] causal mask: synthesized in-kernel, not read.
    float* O = (float*)d_out;

    dim3 grid(64 * NQB);   // (B*H) * (S/QBLK) = 1024 blocks
    attn_fwd<<<grid, 256, 0, stream>>>(Q, K, V, O);
}

// Round 7
// 111.640 us; speedup vs baseline: 1.9796x; 1.3012x over previous
//
#include <hip/hip_runtime.h>

#define SEQ  2048
#define DH   64
#define QBLK 128         // 4 waves x 32 q-rows
#define KBLK 64          // k/v rows per staged tile
#define NQB  (SEQ/QBLK)  // 16
#define NTIL (SEQ/KBLK)  // 32 tiles per bh
#define THR  11.5f       // defer-max threshold (log2 domain)
#define KPAT(r) ((((r)&3)) + 8*((r)>>2))   // 32x32 C/D row pattern
#define WS_NEEDED ((size_t)2 * 64 * SEQ * DH * 2)   // K+V bf16 images = 33.5 MB

typedef short bf16x8 __attribute__((ext_vector_type(8)));   // 8 bf16 bits = 4 VGPRs
typedef float f32x16 __attribute__((ext_vector_type(16)));

union V4U { unsigned int w[4]; bf16x8 v; };

// fp32 -> bf16 bits, round-to-nearest-even
__device__ __forceinline__ short bfbits(float f) {
    unsigned int u = __float_as_uint(f);
    u += 0x7fff + ((u >> 16) & 1);
    return (short)(u >> 16);
}
// packed 2xfp32 -> 2xbf16 in one VALU op
__device__ __forceinline__ unsigned int cvtpk(float lo, float hi) {
    unsigned int r;
    asm("v_cvt_pk_bf16_f32 %0, %1, %2" : "=v"(r) : "v"(lo), "v"(hi));
    return r;
}
// swizzled short-index into a [rows][64] bf16 tile (row stride 128 B)
__device__ __forceinline__ int swz(int row, int col) {
    return row * 64 + (col ^ ((row & 7) << 3));
}
// async global->LDS, 16B per lane; LDS dest = uniform base + lane*16
__device__ __forceinline__ void gload16(const void* g, void* l) {
    __builtin_amdgcn_global_load_lds(
        (const __attribute__((address_space(1))) unsigned int*)g,
        (__attribute__((address_space(3))) unsigned int*)l,
        16, 0, 0);
}

// ================= pre-pass: K/V -> bf16 swizzled tile images =================
__global__ __launch_bounds__(256) void prep_kv(const float* __restrict__ Kg,
                                               const float* __restrict__ Vg,
                                               short* __restrict__ Kimg,
                                               short* __restrict__ Vimg) {
    __shared__ __align__(16) short Vt[64 * 64];
    const int tid = threadIdx.x;
    const int t   = blockIdx.x & (NTIL - 1);
    const int bh  = blockIdx.x / NTIL;
    const int kb  = t * KBLK;

    const float* Kb = Kg + (size_t)bh * SEQ * DH;
    const float* Vb = Vg + (size_t)bh * SEQ * DH;
    short* kim = Kimg + ((size_t)bh * NTIL + t) * 4096;
    short* vim = Vimg + ((size_t)bh * NTIL + t) * 4096;

    // K: row kr, 16-col group -> swizzled image (b128 writes)
    {
        const int kr = tid >> 2, sd0 = (tid & 3) * 16;
        const float* src = Kb + (size_t)(kb + kr) * DH + sd0;
        const float4 a0 = *reinterpret_cast<const float4*>(src);
        const float4 a1 = *reinterpret_cast<const float4*>(src + 4);
        const float4 a2 = *reinterpret_cast<const float4*>(src + 8);
        const float4 a3 = *reinterpret_cast<const float4*>(src + 12);
        V4U u0, u1;
        u0.w[0] = cvtpk(a0.x, a0.y); u0.w[1] = cvtpk(a0.z, a0.w);
        u0.w[2] = cvtpk(a1.x, a1.y); u0.w[3] = cvtpk(a1.z, a1.w);
        u1.w[0] = cvtpk(a2.x, a2.y); u1.w[1] = cvtpk(a2.z, a2.w);
        u1.w[2] = cvtpk(a3.x, a3.y); u1.w[3] = cvtpk(a3.z, a3.w);
        *reinterpret_cast<bf16x8*>(&kim[swz(kr, sd0)])     = u0.v;
        *reinterpret_cast<bf16x8*>(&kim[swz(kr, sd0 + 8)]) = u1.v;
    }
    // V: transpose via LDS (row-uniform u16 scatter), then linear copy-out
    {
        const int vk = tid & 63, vd0 = (tid >> 6) * 16;
        const float* src = Vb + (size_t)(kb + vk) * DH + vd0;
        const float4 b0 = *reinterpret_cast<const float4*>(src);
        const float4 b1 = *reinterpret_cast<const float4*>(src + 4);
        const float4 b2 = *reinterpret_cast<const float4*>(src + 8);
        const float4 b3 = *reinterpret_cast<const float4*>(src + 12);
        const float vv[16] = {b0.x,b0.y,b0.z,b0.w, b1.x,b1.y,b1.z,b1.w,
                              b2.x,b2.y,b2.z,b2.w, b3.x,b3.y,b3.z,b3.w};
        #pragma unroll
        for (int i = 0; i < 16; ++i)
            Vt[swz(vd0 + i, vk)] = bfbits(vv[i]);
    }
    __syncthreads();
    *reinterpret_cast<bf16x8*>(&vim[tid * 16])     = *reinterpret_cast<const bf16x8*>(&Vt[tid * 16]);
    *reinterpret_cast<bf16x8*>(&vim[tid * 16 + 8]) = *reinterpret_cast<const bf16x8*>(&Vt[tid * 16 + 8]);
}

// ================= main kernel: gload_lds staging, dbuf, 1 barrier/tile =================
// stage tile t_ image -> LDS buffer b_ (4 async 16B issues per lane, zero VALU)
#define STAGE(b_, t_) do {                                                   \
    const short* kim_ = kimg + (size_t)(t_) * 4096 + w * 1024 + lane * 8;    \
    const short* vim_ = vimg + (size_t)(t_) * 4096 + w * 1024 + lane * 8;    \
    gload16(kim_,       &Ks[b_][w * 1024]);                                  \
    gload16(kim_ + 512, &Ks[b_][w * 1024 + 512]);                            \
    gload16(vim_,       &Vt[b_][w * 1024]);                                  \
    gload16(vim_ + 512, &Vt[b_][w * 1024 + 512]);                            \
} while (0)

__global__ __launch_bounds__(256, 2) void attn_fwd(const float* __restrict__ Qg,
                                                   const short* __restrict__ Kimg,
                                                   const short* __restrict__ Vimg,
                                                   float* __restrict__ Og) {
    __shared__ __align__(16) short Ks[2][64 * 64];   // K tiles [k][d], swizzled, dbuf
    __shared__ __align__(16) short Vt[2][64 * 64];   // V tiles [d][k], swizzled, dbuf

    const int tid  = threadIdx.x;
    const int w    = tid >> 6;
    const int lane = tid & 63;
    const int h    = lane >> 5;      // half-wave (k-chunk selector)
    const int ql   = lane & 31;      // lane's q-col (S^T) / d-col (O)

    const int qblk = blockIdx.x & (NQB - 1);
    const int bh   = blockIdx.x / NQB;
    const int q0   = qblk * QBLK;
    const int qw   = q0 + w * 32;    // wave's 32 q-rows
    const int q    = qw + ql;        // lane's softmax row

    const float* Qb   = Qg + (size_t)bh * SEQ * DH;
    const short* kimg = Kimg + (size_t)bh * NTIL * 4096;
    const short* vimg = Vimg + (size_t)bh * NTIL * 4096;
    float*       Ob   = Og + (size_t)bh * SEQ * DH;

    const float SC = 0.125f * 1.44269504f;   // 1/sqrt(64) * log2(e)

    const int kend = qw + 32;              // wave's causal k limit (exclusive)
    const int nt   = (q0 + QBLK) / KBLK;   // tiles this block consumes

    STAGE(0, 0);                      // tile 0 in flight; Q conversion hides it

    // ---- Q B-frags (col=lane&31=q, k-chunk d = dc*16 + h*8 + j) ----
    bf16x8 qb[4];
    {
        const float* qp = Qb + (size_t)q * DH + h * 8;
        #pragma unroll
        for (int dc = 0; dc < 4; ++dc) {
            const float4 a = *reinterpret_cast<const float4*>(qp + dc * 16);
            const float4 b = *reinterpret_cast<const float4*>(qp + dc * 16 + 4);
            V4U u;
            u.w[0] = cvtpk(a.x * SC, a.y * SC);
            u.w[1] = cvtpk(a.z * SC, a.w * SC);
            u.w[2] = cvtpk(b.x * SC, b.y * SC);
            u.w[3] = cvtpk(b.z * SC, b.w * SC);
            qb[dc] = u.v;
        }
    }

    f32x16 o0, o1;                    // O[q-rows][d=ql] and [d=32+ql]
    #pragma unroll
    for (int i = 0; i < 16; ++i) { o0[i] = 0.f; o1[i] = 0.f; }
    float m = -1e30f, lsum = 0.f;     // per-lane (q-row) state; lsum is half-row partial

    __syncthreads();                  // buf0 ready (vmcnt drained at barrier)

    for (int t = 0; t < nt; ++t) {
        const int kb  = t * KBLK;
        const int cur = t & 1;
        if (t + 1 < nt) STAGE(cur ^ 1, t + 1);   // issue early: hides under compute

        if (kb < kend) {              // wave-uniform causal skip
            const bool v2 = (kb + 32 < kend);

            // ---- S^T = K Q^T : lane owns q-col ql; rows k = kb + sb*32 + KPAT(r) + 4h ----
            f32x16 sT0, sT1;
            #pragma unroll
            for (int i = 0; i < 16; ++i) sT0[i] = 0.f;
            #pragma unroll
            for (int dc = 0; dc < 4; ++dc) {
                const bf16x8 ka = *reinterpret_cast<const bf16x8*>(&Ks[cur][swz(ql, dc * 16 + h * 8)]);
                sT0 = __builtin_amdgcn_mfma_f32_32x32x16_bf16(ka, qb[dc], sT0, 0, 0, 0);
            }
            if (v2) {
                #pragma unroll
                for (int i = 0; i < 16; ++i) sT1[i] = 0.f;
                #pragma unroll
                for (int dc = 0; dc < 4; ++dc) {
                    const bf16x8 ka = *reinterpret_cast<const bf16x8*>(&Ks[cur][swz(32 + ql, dc * 16 + h * 8)]);
                    sT1 = __builtin_amdgcn_mfma_f32_32x32x16_bf16(ka, qb[dc], sT1, 0, 0, 0);
                }
            }

            // ---- causal mask (boundary sub-blocks only) ----
            if (kb + 31 > qw) {
                #pragma unroll
                for (int r = 0; r < 16; ++r)
                    if (kb + KPAT(r) + 4 * h > q) sT0[r] = -1e30f;
            }
            if (v2 && (kb + 63 > qw)) {
                #pragma unroll
                for (int r = 0; r < 16; ++r)
                    if (kb + 32 + KPAT(r) + 4 * h > q) sT1[r] = -1e30f;
            }

            // ---- in-lane max + defer-max fast path ----
            float mx = sT0[0];
            #pragma unroll
            for (int r = 1; r < 16; ++r) mx = fmaxf(mx, sT0[r]);
            if (v2) {
                #pragma unroll
                for (int r = 0; r < 16; ++r) mx = fmaxf(mx, sT1[r]);
            }
            if (!__all(mx <= m + THR)) {     // slow path: full row max + O/l rescale
                mx = fmaxf(mx, __shfl_xor(mx, 32));
                const float mn  = fmaxf(m, mx);
                const float scl = __builtin_amdgcn_exp2f(m - mn);
                m = mn;
                lsum *= scl;
                #pragma unroll
                for (int r = 0; r < 16; ++r) {
                    const float sr = __shfl(scl, KPAT(r) + 4 * h);
                    o0[r] *= sr; o1[r] *= sr;
                }
            }

            // ---- P = exp2(S^T - m), lane-partial l, pack + half-exchange into A-frags ----
            bf16x8 pa[4];
            {
                float p0[16];
                #pragma unroll
                for (int r = 0; r < 16; ++r) p0[r] = __builtin_amdgcn_exp2f(sT0[r] - m);
                #pragma unroll
                for (int r = 0; r < 16; ++r) lsum += p0[r];
                #pragma unroll
                for (int oct = 0; oct < 2; ++oct) {
                    const unsigned int A0 = cvtpk(p0[oct*8+0], p0[oct*8+1]);
                    const unsigned int A1 = cvtpk(p0[oct*8+2], p0[oct*8+3]);
                    const unsigned int B0 = cvtpk(p0[oct*8+4], p0[oct*8+5]);
                    const unsigned int B1 = cvtpk(p0[oct*8+6], p0[oct*8+7]);
                    const unsigned int s0 = h ? A0 : B0, s1 = h ? A1 : B1;
                    const unsigned int r0 = (unsigned int)__shfl_xor((int)s0, 32);
                    const unsigned int r1 = (unsigned int)__shfl_xor((int)s1, 32);
                    V4U u;
                    u.w[0] = h ? r0 : A0; u.w[1] = h ? r1 : A1;
                    u.w[2] = h ? B0 : r0; u.w[3] = h ? B1 : r1;
                    pa[oct] = u.v;
                }
            }
            if (v2) {
                float p1[16];
                #pragma unroll
                for (int r = 0; r < 16; ++r) p1[r] = __builtin_amdgcn_exp2f(sT1[r] - m);
                #pragma unroll
                for (int r = 0; r < 16; ++r) lsum += p1[r];
                #pragma unroll
                for (int oct = 0; oct < 2; ++oct) {
                    const unsigned int A0 = cvtpk(p1[oct*8+0], p1[oct*8+1]);
                    const unsigned int A1 = cvtpk(p1[oct*8+2], p1[oct*8+3]);
                    const unsigned int B0 = cvtpk(p1[oct*8+4], p1[oct*8+5]);
                    const unsigned int B1 = cvtpk(p1[oct*8+6], p1[oct*8+7]);
                    const unsigned int s0 = h ? A0 : B0, s1 = h ? A1 : B1;
                    const unsigned int r0 = (unsigned int)__shfl_xor((int)s0, 32);
                    const unsigned int r1 = (unsigned int)__shfl_xor((int)s1, 32);
                    V4U u;
                    u.w[0] = h ? r0 : A0; u.w[1] = h ? r1 : A1;
                    u.w[2] = h ? B0 : r0; u.w[3] = h ? B1 : r1;
                    pa[2 + oct] = u.v;
                }
            }

            // ---- O += P V  (B-frags from transposed V tile) ----
            #pragma unroll
            for (int kt = 0; kt < 2; ++kt) {
                const bf16x8 vb0 = *reinterpret_cast<const bf16x8*>(&Vt[cur][swz(ql,      kt * 16 + h * 8)]);
                const bf16x8 vb1 = *reinterpret_cast<const bf16x8*>(&Vt[cur][swz(32 + ql, kt * 16 + h * 8)]);
                o0 = __builtin_amdgcn_mfma_f32_32x32x16_bf16(pa[kt], vb0, o0, 0, 0, 0);
                o1 = __builtin_amdgcn_mfma_f32_32x32x16_bf16(pa[kt], vb1, o1, 0, 0, 0);
            }
            if (v2) {
                #pragma unroll
                for (int kt = 2; kt < 4; ++kt) {
                    const bf16x8 vb0 = *reinterpret_cast<const bf16x8*>(&Vt[cur][swz(ql,      kt * 16 + h * 8)]);
                    const bf16x8 vb1 = *reinterpret_cast<const bf16x8*>(&Vt[cur][swz(32 + ql, kt * 16 + h * 8)]);
                    o0 = __builtin_amdgcn_mfma_f32_32x32x16_bf16(pa[kt], vb0, o0, 0, 0, 0);
                    o1 = __builtin_amdgcn_mfma_f32_32x32x16_bf16(pa[kt], vb1, o1, 0, 0, 0);
                }
            }
        }

        __syncthreads();   // drains vmcnt: next tile ready; buf cur free for t+2
    }

    // ---- epilogue: combine half-row sums, redistribute 1/l, store ----
    lsum += __shfl_xor(lsum, 32);
    const float inv = 1.0f / lsum;
    #pragma unroll
    for (int r = 0; r < 16; ++r) {
        const float ir  = __shfl(inv, KPAT(r) + 4 * h);
        const size_t row = (size_t)(qw + KPAT(r) + 4 * h);
        Ob[row * DH + ql]      = o0[r] * ir;
        Ob[row * DH + 32 + ql] = o1[r] * ir;
    }
}

// ================= fallback (R6 kernel, used if ws too small) =================
#define LOAD_STAGE(kb_) do {                                               \
    const float* ksrc = Kb + (size_t)((kb_) + skr) * DH + sd0;             \
    kr0 = *reinterpret_cast<const float4*>(ksrc);                          \
    kr1 = *reinterpret_cast<const float4*>(ksrc + 4);                      \
    kr2 = *reinterpret_cast<const float4*>(ksrc + 8);                      \
    kr3 = *reinterpret_cast<const float4*>(ksrc + 12);                     \
    const float* vsrc = Vb + (size_t)((kb_) + svk) * DH + svd0;            \
    vr0 = *reinterpret_cast<const float4*>(vsrc);                          \
    vr1 = *reinterpret_cast<const float4*>(vsrc + 4);                      \
    vr2 = *reinterpret_cast<const float4*>(vsrc + 8);                      \
    vr3 = *reinterpret_cast<const float4*>(vsrc + 12);                     \
} while (0)

#define CVT_WRITE(b_) do {                                                 \
    V4U u0, u1;                                                            \
    u0.w[0] = cvtpk(kr0.x, kr0.y); u0.w[1] = cvtpk(kr0.z, kr0.w);          \
    u0.w[2] = cvtpk(kr1.x, kr1.y); u0.w[3] = cvtpk(kr1.z, kr1.w);          \
    u1.w[0] = cvtpk(kr2.x, kr2.y); u1.w[1] = cvtpk(kr2.z, kr2.w);          \
    u1.w[2] = cvtpk(kr3.x, kr3.y); u1.w[3] = cvtpk(kr3.z, kr3.w);          \
    *reinterpret_cast<bf16x8*>(&Ks[b_][swz(skr, sd0)])     = u0.v;         \
    *reinterpret_cast<bf16x8*>(&Ks[b_][swz(skr, sd0 + 8)]) = u1.v;         \
    const float vv[16] = {vr0.x,vr0.y,vr0.z,vr0.w, vr1.x,vr1.y,vr1.z,vr1.w,\
                          vr2.x,vr2.y,vr2.z,vr2.w, vr3.x,vr3.y,vr3.z,vr3.w};\
    _Pragma("unroll")                                                      \
    for (int i_ = 0; i_ < 16; ++i_)                                        \
        Vt[b_][swz(svd0 + i_, svk)] = bfbits(vv[i_]);                      \
} while (0)

__global__ __launch_bounds__(256) void attn_fwd_fb(const float* __restrict__ Qg,
                                                   const float* __restrict__ Kg,
                                                   const float* __restrict__ Vg,
                                                   float* __restrict__ Og) {
    __shared__ __align__(16) short Ks[2][64 * 64];
    __shared__ __align__(16) short Vt[2][64 * 64];

    const int tid  = threadIdx.x;
    const int w    = tid >> 6;
    const int lane = tid & 63;
    const int h    = lane >> 5;
    const int ql   = lane & 31;

    const int qblk = blockIdx.x & (NQB - 1);
    const int bh   = blockIdx.x / NQB;
    const int q0   = qblk * QBLK;
    const int qw   = q0 + w * 32;
    const int q    = qw + ql;

    const float* Qb = Qg + (size_t)bh * SEQ * DH;
    const float* Kb = Kg + (size_t)bh * SEQ * DH;
    const float* Vb = Vg + (size_t)bh * SEQ * DH;
    float*       Ob = Og + (size_t)bh * SEQ * DH;

    const float SC = 0.125f * 1.44269504f;

    const int skr  = tid >> 2;
    const int sd0  = (tid & 3) * 16;
    const int svk  = tid & 63;
    const int svd0 = (tid >> 6) * 16;

    float4 kr0, kr1, kr2, kr3, vr0, vr1, vr2, vr3;
    LOAD_STAGE(0);

    bf16x8 qb[4];
    {
        const float* qp = Qb + (size_t)q * DH + h * 8;
        #pragma unroll
        for (int dc = 0; dc < 4; ++dc) {
            const float4 a = *reinterpret_cast<const float4*>(qp + dc * 16);
            const float4 b = *reinterpret_cast<const float4*>(qp + dc * 16 + 4);
            V4U u;
            u.w[0] = cvtpk(a.x * SC, a.y * SC);
            u.w[1] = cvtpk(a.z * SC, a.w * SC);
            u.w[2] = cvtpk(b.x * SC, b.y * SC);
            u.w[3] = cvtpk(b.z * SC, b.w * SC);
            qb[dc] = u.v;
        }
    }

    f32x16 o0, o1;
    #pragma unroll
    for (int i = 0; i < 16; ++i) { o0[i] = 0.f; o1[i] = 0.f; }
    float m = -1e30f, lsum = 0.f;

    CVT_WRITE(0);
    __syncthreads();

    const int kend = qw + 32;
    const int nt   = (q0 + QBLK) / KBLK;

    for (int t = 0; t < nt; ++t) {
        const int kb  = t * KBLK;
        const int cur = t & 1;
        if (t + 1 < nt) LOAD_STAGE(kb + KBLK);

        if (kb < kend) {
            const bool v2 = (kb + 32 < kend);
            f32x16 sT0, sT1;
            #pragma unroll
            for (int i = 0; i < 16; ++i) sT0[i] = 0.f;
            #pragma unroll
            for (int dc = 0; dc < 4; ++dc) {
                const bf16x8 ka = *reinterpret_cast<const bf16x8*>(&Ks[cur][swz(ql, dc * 16 + h * 8)]);
                sT0 = __builtin_amdgcn_mfma_f32_32x32x16_bf16(ka, qb[dc], sT0, 0, 0, 0);
            }
            if (v2) {
                #pragma unroll
                for (int i = 0; i < 16; ++i) sT1[i] = 0.f;
                #pragma unroll
                for (int dc = 0; dc < 4; ++dc) {
                    const bf16x8 ka = *reinterpret_cast<const bf16x8*>(&Ks[cur][swz(32 + ql, dc * 16 + h * 8)]);
                    sT1 = __builtin_amdgcn_mfma_f32_32x32x16_bf16(ka, qb[dc], sT1, 0, 0, 0);
                }
            }
            if (kb + 31 > qw) {
                #pragma unroll
                for (int r = 0; r < 16; ++r)
                    if (kb + KPAT(r) + 4 * h > q) sT0[r] = -1e30f;
            }
            if (v2 && (kb + 63 > qw)) {
                #pragma unroll
                for (int r = 0; r < 16; ++r)
                    if (kb + 32 + KPAT(r) + 4 * h > q) sT1[r] = -1e30f;
            }
            float mx = sT0[0];
            #pragma unroll
            for (int r = 1; r < 16; ++r) mx = fmaxf(mx, sT0[r]);
            if (v2) {
                #pragma unroll
                for (int r = 0; r < 16; ++r) mx = fmaxf(mx, sT1[r]);
            }
            if (!__all(mx <= m + THR)) {
                mx = fmaxf(mx, __shfl_xor(mx, 32));
                const float mn  = fmaxf(m, mx);
                const float scl = __builtin_amdgcn_exp2f(m - mn);
                m = mn;
                lsum *= scl;
                #pragma unroll
                for (int r = 0; r < 16; ++r) {
                    const float sr = __shfl(scl, KPAT(r) + 4 * h);
                    o0[r] *= sr; o1[r] *= sr;
                }
            }
            bf16x8 pa[4];
            {
                float p0[16];
                #pragma unroll
                for (int r = 0; r < 16; ++r) p0[r] = __builtin_amdgcn_exp2f(sT0[r] - m);
                #pragma unroll
                for (int r = 0; r < 16; ++r) lsum += p0[r];
                #pragma unroll
                for (int oct = 0; oct < 2; ++oct) {
                    const unsigned int A0 = cvtpk(p0[oct*8+0], p0[oct*8+1]);
                    const unsigned int A1 = cvtpk(p0[oct*8+2], p0[oct*8+3]);
                    const unsigned int B0 = cvtpk(p0[oct*8+4], p0[oct*8+5]);
                    const unsigned int B1 = cvtpk(p0[oct*8+6], p0[oct*8+7]);
                    const unsigned int s0 = h ? A0 : B0, s1 = h ? A1 : B1;
                    const unsigned int r0 = (unsigned int)__shfl_xor((int)s0, 32);
                    const unsigned int r1 = (unsigned int)__shfl_xor((int)s1, 32);
                    V4U u;
                    u.w[0] = h ? r0 : A0; u.w[1] = h ? r1 : A1;
                    u.w[2] = h ? B0 : r0; u.w[3] = h ? B1 : r1;
                    pa[oct] = u.v;
                }
            }
            if (v2) {
                float p1[16];
                #pragma unroll
                for (int r = 0; r < 16; ++r) p1[r] = __builtin_amdgcn_exp2f(sT1[r] - m);
                #pragma unroll
                for (int r = 0; r < 16; ++r) lsum += p1[r];
                #pragma unroll
                for (int oct = 0; oct < 2; ++oct) {
                    const unsigned int A0 = cvtpk(p1[oct*8+0], p1[oct*8+1]);
                    const unsigned int A1 = cvtpk(p1[oct*8+2], p1[oct*8+3]);
                    const unsigned int B0 = cvtpk(p1[oct*8+4], p1[oct*8+5]);
                    const unsigned int B1 = cvtpk(p1[oct*8+6], p1[oct*8+7]);
                    const unsigned int s0 = h ? A0 : B0, s1 = h ? A1 : B1;
                    const unsigned int r0 = (unsigned int)__shfl_xor((int)s0, 32);
                    const unsigned int r1 = (unsigned int)__shfl_xor((int)s1, 32);
                    V4U u;
                    u.w[0] = h ? r0 : A0; u.w[1] = h ? r1 : A1;
                    u.w[2] = h ? B0 : r0; u.w[3] = h ? B1 : r1;
                    pa[2 + oct] = u.v;
                }
            }
            #pragma unroll
            for (int kt = 0; kt < 2; ++kt) {
                const bf16x8 vb0 = *reinterpret_cast<const bf16x8*>(&Vt[cur][swz(ql,      kt * 16 + h * 8)]);
                const bf16x8 vb1 = *reinterpret_cast<const bf16x8*>(&Vt[cur][swz(32 + ql, kt * 16 + h * 8)]);
                o0 = __builtin_amdgcn_mfma_f32_32x32x16_bf16(pa[kt], vb0, o0, 0, 0, 0);
                o1 = __builtin_amdgcn_mfma_f32_32x32x16_bf16(pa[kt], vb1, o1, 0, 0, 0);
            }
            if (v2) {
                #pragma unroll
                for (int kt = 2; kt < 4; ++kt) {
                    const bf16x8 vb0 = *reinterpret_cast<const bf16x8*>(&Vt[cur][swz(ql,      kt * 16 + h * 8)]);
                    const bf16x8 vb1 = *reinterpret_cast<const bf16x8*>(&Vt[cur][swz(32 + ql, kt * 16 + h * 8)]);
                    o0 = __builtin_amdgcn_mfma_f32_32x32x16_bf16(pa[kt], vb0, o0, 0, 0, 0);
                    o1 = __builtin_amdgcn_mfma_f32_32x32x16_bf16(pa[kt], vb1, o1, 0, 0, 0);
                }
            }
        }
        if (t + 1 < nt) CVT_WRITE(cur ^ 1);
        __syncthreads();
    }

    lsum += __shfl_xor(lsum, 32);
    const float inv = 1.0f / lsum;
    #pragma unroll
    for (int r = 0; r < 16; ++r) {
        const float ir  = __shfl(inv, KPAT(r) + 4 * h);
        const size_t row = (size_t)(qw + KPAT(r) + 4 * h);
        Ob[row * DH + ql]      = o0[r] * ir;
        Ob[row * DH + 32 + ql] = o1[r] * ir;
    }
}

extern "C" void kernel_launch(void* const* d_in, const int* in_sizes, int n_in,
                              void* d_out, int out_size, void* d_ws, size_t ws_size,
                              hipStream_t stream) {
    const float* Q = (const float*)d_in[0];
    const float* K = (const float*)d_in[1];
    const float* V = (const float*)d_in[2];
    // d_in[3] causal mask: synthesized in-kernel, not read.
    float* O = (float*)d_out;

    if (ws_size >= WS_NEEDED) {
        short* Kimg = (short*)d_ws;
        short* Vimg = Kimg + (size_t)64 * NTIL * 4096;
        prep_kv<<<dim3(64 * NTIL), 256, 0, stream>>>(K, V, Kimg, Vimg);
        attn_fwd<<<dim3(64 * NQB), 256, 0, stream>>>(Q, Kimg, Vimg, O);
    } else {
        attn_fwd_fb<<<dim3(64 * NQB), 256, 0, stream>>>(Q, K, V, O);
    }
}

// Round 8
// 103.185 us; speedup vs baseline: 2.1418x; 1.0819x over previous
//
#include <hip/hip_runtime.h>

#define SEQ  2048
#define DH   64
#define QBLK 128         // 4 waves x 32 q-rows
#define KBLK 64          // k/v rows per staged tile
#define NQB  (SEQ/QBLK)  // 16
#define NTIL (SEQ/KBLK)  // 32 tiles per bh
#define THR  11.5f       // defer-max threshold (log2 domain)
#define KPAT(r) ((((r)&3)) + 8*((r)>>2))   // 32x32 C/D row pattern
#define WS_NEEDED ((size_t)2 * 64 * SEQ * DH * 2)   // K+V bf16 images = 33.5 MB

typedef short bf16x8 __attribute__((ext_vector_type(8)));   // 8 bf16 bits = 4 VGPRs
typedef float f32x16 __attribute__((ext_vector_type(16)));

union V4U { unsigned int w[4]; bf16x8 v; };

// fp32 -> bf16 bits, round-to-nearest-even
__device__ __forceinline__ short bfbits(float f) {
    unsigned int u = __float_as_uint(f);
    u += 0x7fff + ((u >> 16) & 1);
    return (short)(u >> 16);
}
// packed 2xfp32 -> 2xbf16 in one VALU op
__device__ __forceinline__ unsigned int cvtpk(float lo, float hi) {
    unsigned int r;
    asm("v_cvt_pk_bf16_f32 %0, %1, %2" : "=v"(r) : "v"(lo), "v"(hi));
    return r;
}
// swizzled short-index into a [rows][64] bf16 tile (row stride 128 B)
__device__ __forceinline__ int swz(int row, int col) {
    return row * 64 + (col ^ ((row & 7) << 3));
}
// async global->LDS, 16B per lane; LDS dest = uniform base + lane*16
__device__ __forceinline__ void gload16(const void* g, void* l) {
    __builtin_amdgcn_global_load_lds(
        (const __attribute__((address_space(1))) unsigned int*)g,
        (__attribute__((address_space(3))) unsigned int*)l,
        16, 0, 0);
}

// ================= pre-pass: K/V -> bf16 swizzled tile images =================
__global__ __launch_bounds__(256) void prep_kv(const float* __restrict__ Kg,
                                               const float* __restrict__ Vg,
                                               short* __restrict__ Kimg,
                                               short* __restrict__ Vimg) {
    __shared__ __align__(16) short Vt[64 * 64];
    const int tid = threadIdx.x;
    const int t   = blockIdx.x & (NTIL - 1);
    const int bh  = blockIdx.x / NTIL;
    const int kb  = t * KBLK;

    const float* Kb = Kg + (size_t)bh * SEQ * DH;
    const float* Vb = Vg + (size_t)bh * SEQ * DH;
    short* kim = Kimg + ((size_t)bh * NTIL + t) * 4096;
    short* vim = Vimg + ((size_t)bh * NTIL + t) * 4096;

    // K: row kr, 16-col group -> swizzled image (b128 writes)
    {
        const int kr = tid >> 2, sd0 = (tid & 3) * 16;
        const float* src = Kb + (size_t)(kb + kr) * DH + sd0;
        const float4 a0 = *reinterpret_cast<const float4*>(src);
        const float4 a1 = *reinterpret_cast<const float4*>(src + 4);
        const float4 a2 = *reinterpret_cast<const float4*>(src + 8);
        const float4 a3 = *reinterpret_cast<const float4*>(src + 12);
        V4U u0, u1;
        u0.w[0] = cvtpk(a0.x, a0.y); u0.w[1] = cvtpk(a0.z, a0.w);
        u0.w[2] = cvtpk(a1.x, a1.y); u0.w[3] = cvtpk(a1.z, a1.w);
        u1.w[0] = cvtpk(a2.x, a2.y); u1.w[1] = cvtpk(a2.z, a2.w);
        u1.w[2] = cvtpk(a3.x, a3.y); u1.w[3] = cvtpk(a3.z, a3.w);
        *reinterpret_cast<bf16x8*>(&kim[swz(kr, sd0)])     = u0.v;
        *reinterpret_cast<bf16x8*>(&kim[swz(kr, sd0 + 8)]) = u1.v;
    }
    // V: transpose via LDS (row-uniform u16 scatter), then linear copy-out
    {
        const int vk = tid & 63, vd0 = (tid >> 6) * 16;
        const float* src = Vb + (size_t)(kb + vk) * DH + vd0;
        const float4 b0 = *reinterpret_cast<const float4*>(src);
        const float4 b1 = *reinterpret_cast<const float4*>(src + 4);
        const float4 b2 = *reinterpret_cast<const float4*>(src + 8);
        const float4 b3 = *reinterpret_cast<const float4*>(src + 12);
        const float vv[16] = {b0.x,b0.y,b0.z,b0.w, b1.x,b1.y,b1.z,b1.w,
                              b2.x,b2.y,b2.z,b2.w, b3.x,b3.y,b3.z,b3.w};
        #pragma unroll
        for (int i = 0; i < 16; ++i)
            Vt[swz(vd0 + i, vk)] = bfbits(vv[i]);
    }
    __syncthreads();
    *reinterpret_cast<bf16x8*>(&vim[tid * 16])     = *reinterpret_cast<const bf16x8*>(&Vt[tid * 16]);
    *reinterpret_cast<bf16x8*>(&vim[tid * 16 + 8]) = *reinterpret_cast<const bf16x8*>(&Vt[tid * 16 + 8]);
}

// ================= main kernel: gload_lds staging, dbuf, 1 barrier/tile =================
#define STAGE(b_, t_) do {                                                   \
    const short* kim_ = kimg + (size_t)(t_) * 4096 + w * 1024 + lane * 8;    \
    const short* vim_ = vimg + (size_t)(t_) * 4096 + w * 1024 + lane * 8;    \
    gload16(kim_,       &Ks[b_][w * 1024]);                                  \
    gload16(kim_ + 512, &Ks[b_][w * 1024 + 512]);                            \
    gload16(vim_,       &Vt[b_][w * 1024]);                                  \
    gload16(vim_ + 512, &Vt[b_][w * 1024 + 512]);                            \
} while (0)

__global__ __launch_bounds__(256, 2) void attn_fwd(const float* __restrict__ Qg,
                                                   const short* __restrict__ Kimg,
                                                   const short* __restrict__ Vimg,
                                                   float* __restrict__ Og) {
    __shared__ __align__(16) short Ks[2][64 * 64];   // K tiles [k][d], swizzled, dbuf
    __shared__ __align__(16) short Vt[2][64 * 64];   // V tiles [d][k], swizzled, dbuf

    const int tid  = threadIdx.x;
    const int w    = tid >> 6;
    const int lane = tid & 63;
    const int h    = lane >> 5;      // half-wave (k-chunk selector)
    const int ql   = lane & 31;      // lane's q-col (S^T) / d-col (O)

    // ---- causal work-balance permutation ----
    // Block length ~ (2*qblk+2) tile-iters. A CU's successive blocks sit at
    // index stride ~256 (XCD round-robin x 32 CU x 2 resident); 256 = 0 mod 16,
    // so without remap every block on a CU has the SAME qblk (up to 1.9x
    // imbalance). Complementing qblk on (bh>>4) parity makes stride-256
    // successors complementary (j, 15-j): per-CU total constant.
    const int j    = blockIdx.x & (NQB - 1);
    const int bh   = blockIdx.x / NQB;
    const int qblk = ((bh >> 4) & 1) ? (NQB - 1 - j) : j;
    const int q0   = qblk * QBLK;
    const int qw   = q0 + w * 32;    // wave's 32 q-rows
    const int q    = qw + ql;        // lane's softmax row

    const float* Qb   = Qg + (size_t)bh * SEQ * DH;
    const short* kimg = Kimg + (size_t)bh * NTIL * 4096;
    const short* vimg = Vimg + (size_t)bh * NTIL * 4096;
    float*       Ob   = Og + (size_t)bh * SEQ * DH;

    const float SC = 0.125f * 1.44269504f;   // 1/sqrt(64) * log2(e)

    const int kend = qw + 32;              // wave's causal k limit (exclusive)
    const int nt   = (q0 + QBLK) / KBLK;   // tiles this block consumes

    STAGE(0, 0);                      // tile 0 in flight; Q conversion hides it

    // ---- Q B-frags (col=lane&31=q, k-chunk d = dc*16 + h*8 + j) ----
    bf16x8 qb[4];
    {
        const float* qp = Qb + (size_t)q * DH + h * 8;
        #pragma unroll
        for (int dc = 0; dc < 4; ++dc) {
            const float4 a = *reinterpret_cast<const float4*>(qp + dc * 16);
            const float4 b = *reinterpret_cast<const float4*>(qp + dc * 16 + 4);
            V4U u;
            u.w[0] = cvtpk(a.x * SC, a.y * SC);
            u.w[1] = cvtpk(a.z * SC, a.w * SC);
            u.w[2] = cvtpk(b.x * SC, b.y * SC);
            u.w[3] = cvtpk(b.z * SC, b.w * SC);
            qb[dc] = u.v;
        }
    }

    f32x16 o0, o1;                    // O[q-rows][d=ql] and [d=32+ql]
    #pragma unroll
    for (int i = 0; i < 16; ++i) { o0[i] = 0.f; o1[i] = 0.f; }
    float m = -1e30f, lsum = 0.f;     // per-lane (q-row) state; lsum is half-row partial

    __syncthreads();                  // buf0 ready (vmcnt drained at barrier)

    for (int t = 0; t < nt; ++t) {
        const int kb  = t * KBLK;
        const int cur = t & 1;
        if (t + 1 < nt) STAGE(cur ^ 1, t + 1);   // issue early: hides under compute

        if (kb < kend) {              // wave-uniform causal skip
            const bool v2 = (kb + 32 < kend);

            // ---- S^T = K Q^T : lane owns q-col ql; rows k = kb + sb*32 + KPAT(r) + 4h ----
            f32x16 sT0, sT1;
            #pragma unroll
            for (int i = 0; i < 16; ++i) sT0[i] = 0.f;
            __builtin_amdgcn_s_setprio(1);
            #pragma unroll
            for (int dc = 0; dc < 4; ++dc) {
                const bf16x8 ka = *reinterpret_cast<const bf16x8*>(&Ks[cur][swz(ql, dc * 16 + h * 8)]);
                sT0 = __builtin_amdgcn_mfma_f32_32x32x16_bf16(ka, qb[dc], sT0, 0, 0, 0);
            }
            __builtin_amdgcn_s_setprio(0);
            if (v2) {
                #pragma unroll
                for (int i = 0; i < 16; ++i) sT1[i] = 0.f;
                __builtin_amdgcn_s_setprio(1);
                #pragma unroll
                for (int dc = 0; dc < 4; ++dc) {
                    const bf16x8 ka = *reinterpret_cast<const bf16x8*>(&Ks[cur][swz(32 + ql, dc * 16 + h * 8)]);
                    sT1 = __builtin_amdgcn_mfma_f32_32x32x16_bf16(ka, qb[dc], sT1, 0, 0, 0);
                }
                __builtin_amdgcn_s_setprio(0);
            }

            // ---- causal mask (boundary sub-blocks only) ----
            if (kb + 31 > qw) {
                #pragma unroll
                for (int r = 0; r < 16; ++r)
                    if (kb + KPAT(r) + 4 * h > q) sT0[r] = -1e30f;
            }
            if (v2 && (kb + 63 > qw)) {
                #pragma unroll
                for (int r = 0; r < 16; ++r)
                    if (kb + 32 + KPAT(r) + 4 * h > q) sT1[r] = -1e30f;
            }

            // ---- in-lane max + defer-max fast path ----
            float mx = sT0[0];
            #pragma unroll
            for (int r = 1; r < 16; ++r) mx = fmaxf(mx, sT0[r]);
            if (v2) {
                #pragma unroll
                for (int r = 0; r < 16; ++r) mx = fmaxf(mx, sT1[r]);
            }
            if (!__all(mx <= m + THR)) {     // slow path: full row max + O/l rescale
                mx = fmaxf(mx, __shfl_xor(mx, 32));
                const float mn  = fmaxf(m, mx);
                const float scl = __builtin_amdgcn_exp2f(m - mn);
                m = mn;
                lsum *= scl;
                #pragma unroll
                for (int r = 0; r < 16; ++r) {
                    const float sr = __shfl(scl, KPAT(r) + 4 * h);
                    o0[r] *= sr; o1[r] *= sr;
                }
            }

            // ---- P = exp2(S^T - m), lane-partial l, pack + half-exchange into A-frags ----
            bf16x8 pa[4];
            {
                float p0[16];
                #pragma unroll
                for (int r = 0; r < 16; ++r) p0[r] = __builtin_amdgcn_exp2f(sT0[r] - m);
                #pragma unroll
                for (int r = 0; r < 16; ++r) lsum += p0[r];
                #pragma unroll
                for (int oct = 0; oct < 2; ++oct) {
                    const unsigned int A0 = cvtpk(p0[oct*8+0], p0[oct*8+1]);
                    const unsigned int A1 = cvtpk(p0[oct*8+2], p0[oct*8+3]);
                    const unsigned int B0 = cvtpk(p0[oct*8+4], p0[oct*8+5]);
                    const unsigned int B1 = cvtpk(p0[oct*8+6], p0[oct*8+7]);
                    const unsigned int s0 = h ? A0 : B0, s1 = h ? A1 : B1;
                    const unsigned int r0 = (unsigned int)__shfl_xor((int)s0, 32);
                    const unsigned int r1 = (unsigned int)__shfl_xor((int)s1, 32);
                    V4U u;
                    u.w[0] = h ? r0 : A0; u.w[1] = h ? r1 : A1;
                    u.w[2] = h ? B0 : r0; u.w[3] = h ? B1 : r1;
                    pa[oct] = u.v;
                }
            }
            if (v2) {
                float p1[16];
                #pragma unroll
                for (int r = 0; r < 16; ++r) p1[r] = __builtin_amdgcn_exp2f(sT1[r] - m);
                #pragma unroll
                for (int r = 0; r < 16; ++r) lsum += p1[r];
                #pragma unroll
                for (int oct = 0; oct < 2; ++oct) {
                    const unsigned int A0 = cvtpk(p1[oct*8+0], p1[oct*8+1]);
                    const unsigned int A1 = cvtpk(p1[oct*8+2], p1[oct*8+3]);
                    const unsigned int B0 = cvtpk(p1[oct*8+4], p1[oct*8+5]);
                    const unsigned int B1 = cvtpk(p1[oct*8+6], p1[oct*8+7]);
                    const unsigned int s0 = h ? A0 : B0, s1 = h ? A1 : B1;
                    const unsigned int r0 = (unsigned int)__shfl_xor((int)s0, 32);
                    const unsigned int r1 = (unsigned int)__shfl_xor((int)s1, 32);
                    V4U u;
                    u.w[0] = h ? r0 : A0; u.w[1] = h ? r1 : A1;
                    u.w[2] = h ? B0 : r0; u.w[3] = h ? B1 : r1;
                    pa[2 + oct] = u.v;
                }
            }

            // ---- O += P V  (B-frags from transposed V tile) ----
            __builtin_amdgcn_s_setprio(1);
            #pragma unroll
            for (int kt = 0; kt < 2; ++kt) {
                const bf16x8 vb0 = *reinterpret_cast<const bf16x8*>(&Vt[cur][swz(ql,      kt * 16 + h * 8)]);
                const bf16x8 vb1 = *reinterpret_cast<const bf16x8*>(&Vt[cur][swz(32 + ql, kt * 16 + h * 8)]);
                o0 = __builtin_amdgcn_mfma_f32_32x32x16_bf16(pa[kt], vb0, o0, 0, 0, 0);
                o1 = __builtin_amdgcn_mfma_f32_32x32x16_bf16(pa[kt], vb1, o1, 0, 0, 0);
            }
            __builtin_amdgcn_s_setprio(0);
            if (v2) {
                __builtin_amdgcn_s_setprio(1);
                #pragma unroll
                for (int kt = 2; kt < 4; ++kt) {
                    const bf16x8 vb0 = *reinterpret_cast<const bf16x8*>(&Vt[cur][swz(ql,      kt * 16 + h * 8)]);
                    const bf16x8 vb1 = *reinterpret_cast<const bf16x8*>(&Vt[cur][swz(32 + ql, kt * 16 + h * 8)]);
                    o0 = __builtin_amdgcn_mfma_f32_32x32x16_bf16(pa[kt], vb0, o0, 0, 0, 0);
                    o1 = __builtin_amdgcn_mfma_f32_32x32x16_bf16(pa[kt], vb1, o1, 0, 0, 0);
                }
                __builtin_amdgcn_s_setprio(0);
            }
        }

        __syncthreads();   // drains vmcnt: next tile ready; buf cur free for t+2
    }

    // ---- epilogue: combine half-row sums, redistribute 1/l, store ----
    lsum += __shfl_xor(lsum, 32);
    const float inv = 1.0f / lsum;
    #pragma unroll
    for (int r = 0; r < 16; ++r) {
        const float ir  = __shfl(inv, KPAT(r) + 4 * h);
        const size_t row = (size_t)(qw + KPAT(r) + 4 * h);
        Ob[row * DH + ql]      = o0[r] * ir;
        Ob[row * DH + 32 + ql] = o1[r] * ir;
    }
}

// ================= fallback (reg-staged, used if ws too small) =================
#define LOAD_STAGE(kb_) do {                                               \
    const float* ksrc = Kb + (size_t)((kb_) + skr) * DH + sd0;             \
    kr0 = *reinterpret_cast<const float4*>(ksrc);                          \
    kr1 = *reinterpret_cast<const float4*>(ksrc + 4);                      \
    kr2 = *reinterpret_cast<const float4*>(ksrc + 8);                      \
    kr3 = *reinterpret_cast<const float4*>(ksrc + 12);                     \
    const float* vsrc = Vb + (size_t)((kb_) + svk) * DH + svd0;            \
    vr0 = *reinterpret_cast<const float4*>(vsrc);                          \
    vr1 = *reinterpret_cast<const float4*>(vsrc + 4);                      \
    vr2 = *reinterpret_cast<const float4*>(vsrc + 8);                      \
    vr3 = *reinterpret_cast<const float4*>(vsrc + 12);                     \
} while (0)

#define CVT_WRITE(b_) do {                                                 \
    V4U u0, u1;                                                            \
    u0.w[0] = cvtpk(kr0.x, kr0.y); u0.w[1] = cvtpk(kr0.z, kr0.w);          \
    u0.w[2] = cvtpk(kr1.x, kr1.y); u0.w[3] = cvtpk(kr1.z, kr1.w);          \
    u1.w[0] = cvtpk(kr2.x, kr2.y); u1.w[1] = cvtpk(kr2.z, kr2.w);          \
    u1.w[2] = cvtpk(kr3.x, kr3.y); u1.w[3] = cvtpk(kr3.z, kr3.w);          \
    *reinterpret_cast<bf16x8*>(&Ks[b_][swz(skr, sd0)])     = u0.v;         \
    *reinterpret_cast<bf16x8*>(&Ks[b_][swz(skr, sd0 + 8)]) = u1.v;         \
    const float vv[16] = {vr0.x,vr0.y,vr0.z,vr0.w, vr1.x,vr1.y,vr1.z,vr1.w,\
                          vr2.x,vr2.y,vr2.z,vr2.w, vr3.x,vr3.y,vr3.z,vr3.w};\
    _Pragma("unroll")                                                      \
    for (int i_ = 0; i_ < 16; ++i_)                                        \
        Vt[b_][swz(svd0 + i_, svk)] = bfbits(vv[i_]);                      \
} while (0)

__global__ __launch_bounds__(256) void attn_fwd_fb(const float* __restrict__ Qg,
                                                   const float* __restrict__ Kg,
                                                   const float* __restrict__ Vg,
                                                   float* __restrict__ Og) {
    __shared__ __align__(16) short Ks[2][64 * 64];
    __shared__ __align__(16) short Vt[2][64 * 64];

    const int tid  = threadIdx.x;
    const int w    = tid >> 6;
    const int lane = tid & 63;
    const int h    = lane >> 5;
    const int ql   = lane & 31;

    const int j    = blockIdx.x & (NQB - 1);
    const int bh   = blockIdx.x / NQB;
    const int qblk = ((bh >> 4) & 1) ? (NQB - 1 - j) : j;
    const int q0   = qblk * QBLK;
    const int qw   = q0 + w * 32;
    const int q    = qw + ql;

    const float* Qb = Qg + (size_t)bh * SEQ * DH;
    const float* Kb = Kg + (size_t)bh * SEQ * DH;
    const float* Vb = Vg + (size_t)bh * SEQ * DH;
    float*       Ob = Og + (size_t)bh * SEQ * DH;

    const float SC = 0.125f * 1.44269504f;

    const int skr  = tid >> 2;
    const int sd0  = (tid & 3) * 16;
    const int svk  = tid & 63;
    const int svd0 = (tid >> 6) * 16;

    float4 kr0, kr1, kr2, kr3, vr0, vr1, vr2, vr3;
    LOAD_STAGE(0);

    bf16x8 qb[4];
    {
        const float* qp = Qb + (size_t)q * DH + h * 8;
        #pragma unroll
        for (int dc = 0; dc < 4; ++dc) {
            const float4 a = *reinterpret_cast<const float4*>(qp + dc * 16);
            const float4 b = *reinterpret_cast<const float4*>(qp + dc * 16 + 4);
            V4U u;
            u.w[0] = cvtpk(a.x * SC, a.y * SC);
            u.w[1] = cvtpk(a.z * SC, a.w * SC);
            u.w[2] = cvtpk(b.x * SC, b.y * SC);
            u.w[3] = cvtpk(b.z * SC, b.w * SC);
            qb[dc] = u.v;
        }
    }

    f32x16 o0, o1;
    #pragma unroll
    for (int i = 0; i < 16; ++i) { o0[i] = 0.f; o1[i] = 0.f; }
    float m = -1e30f, lsum = 0.f;

    CVT_WRITE(0);
    __syncthreads();

    const int kend = qw + 32;
    const int nt   = (q0 + QBLK) / KBLK;

    for (int t = 0; t < nt; ++t) {
        const int kb  = t * KBLK;
        const int cur = t & 1;
        if (t + 1 < nt) LOAD_STAGE(kb + KBLK);

        if (kb < kend) {
            const bool v2 = (kb + 32 < kend);
            f32x16 sT0, sT1;
            #pragma unroll
            for (int i = 0; i < 16; ++i) sT0[i] = 0.f;
            #pragma unroll
            for (int dc = 0; dc < 4; ++dc) {
                const bf16x8 ka = *reinterpret_cast<const bf16x8*>(&Ks[cur][swz(ql, dc * 16 + h * 8)]);
                sT0 = __builtin_amdgcn_mfma_f32_32x32x16_bf16(ka, qb[dc], sT0, 0, 0, 0);
            }
            if (v2) {
                #pragma unroll
                for (int i = 0; i < 16; ++i) sT1[i] = 0.f;
                #pragma unroll
                for (int dc = 0; dc < 4; ++dc) {
                    const bf16x8 ka = *reinterpret_cast<const bf16x8*>(&Ks[cur][swz(32 + ql, dc * 16 + h * 8)]);
                    sT1 = __builtin_amdgcn_mfma_f32_32x32x16_bf16(ka, qb[dc], sT1, 0, 0, 0);
                }
            }
            if (kb + 31 > qw) {
                #pragma unroll
                for (int r = 0; r < 16; ++r)
                    if (kb + KPAT(r) + 4 * h > q) sT0[r] = -1e30f;
            }
            if (v2 && (kb + 63 > qw)) {
                #pragma unroll
                for (int r = 0; r < 16; ++r)
                    if (kb + 32 + KPAT(r) + 4 * h > q) sT1[r] = -1e30f;
            }
            float mx = sT0[0];
            #pragma unroll
            for (int r = 1; r < 16; ++r) mx = fmaxf(mx, sT0[r]);
            if (v2) {
                #pragma unroll
                for (int r = 0; r < 16; ++r) mx = fmaxf(mx, sT1[r]);
            }
            if (!__all(mx <= m + THR)) {
                mx = fmaxf(mx, __shfl_xor(mx, 32));
                const float mn  = fmaxf(m, mx);
                const float scl = __builtin_amdgcn_exp2f(m - mn);
                m = mn;
                lsum *= scl;
                #pragma unroll
                for (int r = 0; r < 16; ++r) {
                    const float sr = __shfl(scl, KPAT(r) + 4 * h);
                    o0[r] *= sr; o1[r] *= sr;
                }
            }
            bf16x8 pa[4];
            {
                float p0[16];
                #pragma unroll
                for (int r = 0; r < 16; ++r) p0[r] = __builtin_amdgcn_exp2f(sT0[r] - m);
                #pragma unroll
                for (int r = 0; r < 16; ++r) lsum += p0[r];
                #pragma unroll
                for (int oct = 0; oct < 2; ++oct) {
                    const unsigned int A0 = cvtpk(p0[oct*8+0], p0[oct*8+1]);
                    const unsigned int A1 = cvtpk(p0[oct*8+2], p0[oct*8+3]);
                    const unsigned int B0 = cvtpk(p0[oct*8+4], p0[oct*8+5]);
                    const unsigned int B1 = cvtpk(p0[oct*8+6], p0[oct*8+7]);
                    const unsigned int s0 = h ? A0 : B0, s1 = h ? A1 : B1;
                    const unsigned int r0 = (unsigned int)__shfl_xor((int)s0, 32);
                    const unsigned int r1 = (unsigned int)__shfl_xor((int)s1, 32);
                    V4U u;
                    u.w[0] = h ? r0 : A0; u.w[1] = h ? r1 : A1;
                    u.w[2] = h ? B0 : r0; u.w[3] = h ? B1 : r1;
                    pa[oct] = u.v;
                }
            }
            if (v2) {
                float p1[16];
                #pragma unroll
                for (int r = 0; r < 16; ++r) p1[r] = __builtin_amdgcn_exp2f(sT1[r] - m);
                #pragma unroll
                for (int r = 0; r < 16; ++r) lsum += p1[r];
                #pragma unroll
                for (int oct = 0; oct < 2; ++oct) {
                    const unsigned int A0 = cvtpk(p1[oct*8+0], p1[oct*8+1]);
                    const unsigned int A1 = cvtpk(p1[oct*8+2], p1[oct*8+3]);
                    const unsigned int B0 = cvtpk(p1[oct*8+4], p1[oct*8+5]);
                    const unsigned int B1 = cvtpk(p1[oct*8+6], p1[oct*8+7]);
                    const unsigned int s0 = h ? A0 : B0, s1 = h ? A1 : B1;
                    const unsigned int r0 = (unsigned int)__shfl_xor((int)s0, 32);
                    const unsigned int r1 = (unsigned int)__shfl_xor((int)s1, 32);
                    V4U u;
                    u.w[0] = h ? r0 : A0; u.w[1] = h ? r1 : A1;
                    u.w[2] = h ? B0 : r0; u.w[3] = h ? B1 : r1;
                    pa[2 + oct] = u.v;
                }
            }
            #pragma unroll
            for (int kt = 0; kt < 2; ++kt) {
                const bf16x8 vb0 = *reinterpret_cast<const bf16x8*>(&Vt[cur][swz(ql,      kt * 16 + h * 8)]);
                const bf16x8 vb1 = *reinterpret_cast<const bf16x8*>(&Vt[cur][swz(32 + ql, kt * 16 + h * 8)]);
                o0 = __builtin_amdgcn_mfma_f32_32x32x16_bf16(pa[kt], vb0, o0, 0, 0, 0);
                o1 = __builtin_amdgcn_mfma_f32_32x32x16_bf16(pa[kt], vb1, o1, 0, 0, 0);
            }
            if (v2) {
                #pragma unroll
                for (int kt = 2; kt < 4; ++kt) {
                    const bf16x8 vb0 = *reinterpret_cast<const bf16x8*>(&Vt[cur][swz(ql,      kt * 16 + h * 8)]);
                    const bf16x8 vb1 = *reinterpret_cast<const bf16x8*>(&Vt[cur][swz(32 + ql, kt * 16 + h * 8)]);
                    o0 = __builtin_amdgcn_mfma_f32_32x32x16_bf16(pa[kt], vb0, o0, 0, 0, 0);
                    o1 = __builtin_amdgcn_mfma_f32_32x32x16_bf16(pa[kt], vb1, o1, 0, 0, 0);
                }
            }
        }
        if (t + 1 < nt) CVT_WRITE(cur ^ 1);
        __syncthreads();
    }

    lsum += __shfl_xor(lsum, 32);
    const float inv = 1.0f / lsum;
    #pragma unroll
    for (int r = 0; r < 16; ++r) {
        const float ir  = __shfl(inv, KPAT(r) + 4 * h);
        const size_t row = (size_t)(qw + KPAT(r) + 4 * h);
        Ob[row * DH + ql]      = o0[r] * ir;
        Ob[row * DH + 32 + ql] = o1[r] * ir;
    }
}

extern "C" void kernel_launch(void* const* d_in, const int* in_sizes, int n_in,
                              void* d_out, int out_size, void* d_ws, size_t ws_size,
                              hipStream_t stream) {
    const float* Q = (const float*)d_in[0];
    const float* K = (const float*)d_in[1];
    const float* V = (const float*)d_in[2];
    // d_in[3] causal mask: synthesized in-kernel, not read.
    float* O = (float*)d_out;

    if (ws_size >= WS_NEEDED) {
        short* Kimg = (short*)d_ws;
        short* Vimg = Kimg + (size_t)64 * NTIL * 4096;
        prep_kv<<<dim3(64 * NTIL), 256, 0, stream>>>(K, V, Kimg, Vimg);
        attn_fwd<<<dim3(64 * NQB), 256, 0, stream>>>(Q, Kimg, Vimg, O);
    } else {
        attn_fwd_fb<<<dim3(64 * NQB), 256, 0, stream>>>(Q, K, V, O);
    }
}

// Round 9
// 85.292 us; speedup vs baseline: 2.5911x; 1.2098x over previous
//
#include <hip/hip_runtime.h>

#define SEQ  2048
#define DH   64
#define QBLK 128         // q rows per q-block = 4 waves x 32
#define KBLK 64          // k/v rows per staged tile
#define NQB  (SEQ/QBLK)  // 16
#define NTIL (SEQ/KBLK)  // 32 tiles per bh
#define THR  11.5f       // defer-max threshold (log2 domain)
#define KPAT(r) ((((r)&3)) + 8*((r)>>2))   // 32x32 C/D row pattern
#define WS_NEEDED ((size_t)2 * 64 * SEQ * DH * 2)   // K+V bf16 images = 33.5 MB

typedef short bf16x8 __attribute__((ext_vector_type(8)));   // 8 bf16 bits = 4 VGPRs
typedef float f32x16 __attribute__((ext_vector_type(16)));

union V4U { unsigned int w[4]; bf16x8 v; };

// fp32 -> bf16 bits, round-to-nearest-even
__device__ __forceinline__ short bfbits(float f) {
    unsigned int u = __float_as_uint(f);
    u += 0x7fff + ((u >> 16) & 1);
    return (short)(u >> 16);
}
// packed 2xfp32 -> 2xbf16 in one VALU op
__device__ __forceinline__ unsigned int cvtpk(float lo, float hi) {
    unsigned int r;
    asm("v_cvt_pk_bf16_f32 %0, %1, %2" : "=v"(r) : "v"(lo), "v"(hi));
    return r;
}
// swizzled short-index into a [rows][64] bf16 tile (row stride 128 B)
__device__ __forceinline__ int swz(int row, int col) {
    return row * 64 + (col ^ ((row & 7) << 3));
}
// async global->LDS, 16B per lane; LDS dest = uniform base + lane*16
__device__ __forceinline__ void gload16(const void* g, void* l) {
    __builtin_amdgcn_global_load_lds(
        (const __attribute__((address_space(1))) unsigned int*)g,
        (__attribute__((address_space(3))) unsigned int*)l,
        16, 0, 0);
}

// ================= pre-pass: K/V -> bf16 swizzled tile images =================
__global__ __launch_bounds__(256) void prep_kv(const float* __restrict__ Kg,
                                               const float* __restrict__ Vg,
                                               short* __restrict__ Kimg,
                                               short* __restrict__ Vimg) {
    __shared__ __align__(16) short Vt[64 * 64];
    const int tid = threadIdx.x;
    const int t   = blockIdx.x & (NTIL - 1);
    const int bh  = blockIdx.x / NTIL;
    const int kb  = t * KBLK;

    const float* Kb = Kg + (size_t)bh * SEQ * DH;
    const float* Vb = Vg + (size_t)bh * SEQ * DH;
    short* kim = Kimg + ((size_t)bh * NTIL + t) * 4096;
    short* vim = Vimg + ((size_t)bh * NTIL + t) * 4096;

    {
        const int kr = tid >> 2, sd0 = (tid & 3) * 16;
        const float* src = Kb + (size_t)(kb + kr) * DH + sd0;
        const float4 a0 = *reinterpret_cast<const float4*>(src);
        const float4 a1 = *reinterpret_cast<const float4*>(src + 4);
        const float4 a2 = *reinterpret_cast<const float4*>(src + 8);
        const float4 a3 = *reinterpret_cast<const float4*>(src + 12);
        V4U u0, u1;
        u0.w[0] = cvtpk(a0.x, a0.y); u0.w[1] = cvtpk(a0.z, a0.w);
        u0.w[2] = cvtpk(a1.x, a1.y); u0.w[3] = cvtpk(a1.z, a1.w);
        u1.w[0] = cvtpk(a2.x, a2.y); u1.w[1] = cvtpk(a2.z, a2.w);
        u1.w[2] = cvtpk(a3.x, a3.y); u1.w[3] = cvtpk(a3.z, a3.w);
        *reinterpret_cast<bf16x8*>(&kim[swz(kr, sd0)])     = u0.v;
        *reinterpret_cast<bf16x8*>(&kim[swz(kr, sd0 + 8)]) = u1.v;
    }
    {
        const int vk = tid & 63, vd0 = (tid >> 6) * 16;
        const float* src = Vb + (size_t)(kb + vk) * DH + vd0;
        const float4 b0 = *reinterpret_cast<const float4*>(src);
        const float4 b1 = *reinterpret_cast<const float4*>(src + 4);
        const float4 b2 = *reinterpret_cast<const float4*>(src + 8);
        const float4 b3 = *reinterpret_cast<const float4*>(src + 12);
        const float vv[16] = {b0.x,b0.y,b0.z,b0.w, b1.x,b1.y,b1.z,b1.w,
                              b2.x,b2.y,b2.z,b2.w, b3.x,b3.y,b3.z,b3.w};
        #pragma unroll
        for (int i = 0; i < 16; ++i)
            Vt[swz(vd0 + i, vk)] = bfbits(vv[i]);
    }
    __syncthreads();
    *reinterpret_cast<bf16x8*>(&vim[tid * 16])     = *reinterpret_cast<const bf16x8*>(&Vt[tid * 16]);
    *reinterpret_cast<bf16x8*>(&vim[tid * 16 + 8]) = *reinterpret_cast<const bf16x8*>(&Vt[tid * 16 + 8]);
}

// ================= main kernel: paired q-blocks (j, 15-j), uniform work =================
#define STAGE(b_, t_) do {                                                   \
    const short* kim_ = kimg + (size_t)(t_) * 4096 + w * 1024 + lane * 8;    \
    const short* vim_ = vimg + (size_t)(t_) * 4096 + w * 1024 + lane * 8;    \
    gload16(kim_,       &Ks[b_][w * 1024]);                                  \
    gload16(kim_ + 512, &Ks[b_][w * 1024 + 512]);                            \
    gload16(vim_,       &Vt[b_][w * 1024]);                                  \
    gload16(vim_ + 512, &Vt[b_][w * 1024 + 512]);                            \
} while (0)

// per-q-block per-tile compute (wave-uniform early-out on causal limit)
__device__ __forceinline__ void tile_compute(
    const short* __restrict__ Ksb, const short* __restrict__ Vtb,
    int kb, int kend, int qw, int q, int h, int ql,
    const bf16x8 (&qb)[4], f32x16& o0, f32x16& o1, float& m, float& lsum)
{
    if (kb >= kend) return;
    const bool v2 = (kb + 32 < kend);

    // ---- S^T = K Q^T : lane owns q-col ql; rows k = kb + sb*32 + KPAT(r) + 4h ----
    f32x16 sT0, sT1;
    #pragma unroll
    for (int i = 0; i < 16; ++i) sT0[i] = 0.f;
    __builtin_amdgcn_s_setprio(1);
    #pragma unroll
    for (int dc = 0; dc < 4; ++dc) {
        const bf16x8 ka = *reinterpret_cast<const bf16x8*>(&Ksb[swz(ql, dc * 16 + h * 8)]);
        sT0 = __builtin_amdgcn_mfma_f32_32x32x16_bf16(ka, qb[dc], sT0, 0, 0, 0);
    }
    __builtin_amdgcn_s_setprio(0);
    if (v2) {
        #pragma unroll
        for (int i = 0; i < 16; ++i) sT1[i] = 0.f;
        __builtin_amdgcn_s_setprio(1);
        #pragma unroll
        for (int dc = 0; dc < 4; ++dc) {
            const bf16x8 ka = *reinterpret_cast<const bf16x8*>(&Ksb[swz(32 + ql, dc * 16 + h * 8)]);
            sT1 = __builtin_amdgcn_mfma_f32_32x32x16_bf16(ka, qb[dc], sT1, 0, 0, 0);
        }
        __builtin_amdgcn_s_setprio(0);
    }

    // ---- causal mask (boundary sub-blocks only) ----
    if (kb + 31 > qw) {
        #pragma unroll
        for (int r = 0; r < 16; ++r)
            if (kb + KPAT(r) + 4 * h > q) sT0[r] = -1e30f;
    }
    if (v2 && (kb + 63 > qw)) {
        #pragma unroll
        for (int r = 0; r < 16; ++r)
            if (kb + 32 + KPAT(r) + 4 * h > q) sT1[r] = -1e30f;
    }

    // ---- in-lane max + defer-max fast path ----
    float mx = sT0[0];
    #pragma unroll
    for (int r = 1; r < 16; ++r) mx = fmaxf(mx, sT0[r]);
    if (v2) {
        #pragma unroll
        for (int r = 0; r < 16; ++r) mx = fmaxf(mx, sT1[r]);
    }
    if (!__all(mx <= m + THR)) {     // slow path: full row max + O/l rescale
        mx = fmaxf(mx, __shfl_xor(mx, 32));
        const float mn  = fmaxf(m, mx);
        const float scl = __builtin_amdgcn_exp2f(m - mn);
        m = mn;
        lsum *= scl;
        #pragma unroll
        for (int r = 0; r < 16; ++r) {
            const float sr = __shfl(scl, KPAT(r) + 4 * h);
            o0[r] *= sr; o1[r] *= sr;
        }
    }

    // ---- P = exp2(S^T - m), lane-partial l, pack + half-exchange into A-frags ----
    bf16x8 pa[4];
    {
        float p0[16];
        #pragma unroll
        for (int r = 0; r < 16; ++r) p0[r] = __builtin_amdgcn_exp2f(sT0[r] - m);
        #pragma unroll
        for (int r = 0; r < 16; ++r) lsum += p0[r];
        #pragma unroll
        for (int oct = 0; oct < 2; ++oct) {
            const unsigned int A0 = cvtpk(p0[oct*8+0], p0[oct*8+1]);
            const unsigned int A1 = cvtpk(p0[oct*8+2], p0[oct*8+3]);
            const unsigned int B0 = cvtpk(p0[oct*8+4], p0[oct*8+5]);
            const unsigned int B1 = cvtpk(p0[oct*8+6], p0[oct*8+7]);
            const unsigned int s0 = h ? A0 : B0, s1 = h ? A1 : B1;
            const unsigned int r0 = (unsigned int)__shfl_xor((int)s0, 32);
            const unsigned int r1 = (unsigned int)__shfl_xor((int)s1, 32);
            V4U u;
            u.w[0] = h ? r0 : A0; u.w[1] = h ? r1 : A1;
            u.w[2] = h ? B0 : r0; u.w[3] = h ? B1 : r1;
            pa[oct] = u.v;
        }
    }
    if (v2) {
        float p1[16];
        #pragma unroll
        for (int r = 0; r < 16; ++r) p1[r] = __builtin_amdgcn_exp2f(sT1[r] - m);
        #pragma unroll
        for (int r = 0; r < 16; ++r) lsum += p1[r];
        #pragma unroll
        for (int oct = 0; oct < 2; ++oct) {
            const unsigned int A0 = cvtpk(p1[oct*8+0], p1[oct*8+1]);
            const unsigned int A1 = cvtpk(p1[oct*8+2], p1[oct*8+3]);
            const unsigned int B0 = cvtpk(p1[oct*8+4], p1[oct*8+5]);
            const unsigned int B1 = cvtpk(p1[oct*8+6], p1[oct*8+7]);
            const unsigned int s0 = h ? A0 : B0, s1 = h ? A1 : B1;
            const unsigned int r0 = (unsigned int)__shfl_xor((int)s0, 32);
            const unsigned int r1 = (unsigned int)__shfl_xor((int)s1, 32);
            V4U u;
            u.w[0] = h ? r0 : A0; u.w[1] = h ? r1 : A1;
            u.w[2] = h ? B0 : r0; u.w[3] = h ? B1 : r1;
            pa[2 + oct] = u.v;
        }
    }

    // ---- O += P V  (B-frags from transposed V tile) ----
    __builtin_amdgcn_s_setprio(1);
    #pragma unroll
    for (int kt = 0; kt < 2; ++kt) {
        const bf16x8 vb0 = *reinterpret_cast<const bf16x8*>(&Vtb[swz(ql,      kt * 16 + h * 8)]);
        const bf16x8 vb1 = *reinterpret_cast<const bf16x8*>(&Vtb[swz(32 + ql, kt * 16 + h * 8)]);
        o0 = __builtin_amdgcn_mfma_f32_32x32x16_bf16(pa[kt], vb0, o0, 0, 0, 0);
        o1 = __builtin_amdgcn_mfma_f32_32x32x16_bf16(pa[kt], vb1, o1, 0, 0, 0);
    }
    __builtin_amdgcn_s_setprio(0);
    if (v2) {
        __builtin_amdgcn_s_setprio(1);
        #pragma unroll
        for (int kt = 2; kt < 4; ++kt) {
            const bf16x8 vb0 = *reinterpret_cast<const bf16x8*>(&Vtb[swz(ql,      kt * 16 + h * 8)]);
            const bf16x8 vb1 = *reinterpret_cast<const bf16x8*>(&Vtb[swz(32 + ql, kt * 16 + h * 8)]);
            o0 = __builtin_amdgcn_mfma_f32_32x32x16_bf16(pa[kt], vb0, o0, 0, 0, 0);
            o1 = __builtin_amdgcn_mfma_f32_32x32x16_bf16(pa[kt], vb1, o1, 0, 0, 0);
        }
        __builtin_amdgcn_s_setprio(0);
    }
}

__device__ __forceinline__ void load_qfrags(const float* Qb, int q, int h, float SC,
                                            bf16x8 (&qb)[4]) {
    const float* qp = Qb + (size_t)q * DH + h * 8;
    #pragma unroll
    for (int dc = 0; dc < 4; ++dc) {
        const float4 a = *reinterpret_cast<const float4*>(qp + dc * 16);
        const float4 b = *reinterpret_cast<const float4*>(qp + dc * 16 + 4);
        V4U u;
        u.w[0] = cvtpk(a.x * SC, a.y * SC);
        u.w[1] = cvtpk(a.z * SC, a.w * SC);
        u.w[2] = cvtpk(b.x * SC, b.y * SC);
        u.w[3] = cvtpk(b.z * SC, b.w * SC);
        qb[dc] = u.v;
    }
}

__device__ __forceinline__ void epilogue_store(float* Ob, int qw, int h, int ql,
                                               const f32x16& o0, const f32x16& o1,
                                               float lsum) {
    lsum += __shfl_xor(lsum, 32);
    const float inv = 1.0f / lsum;
    #pragma unroll
    for (int r = 0; r < 16; ++r) {
        const float ir  = __shfl(inv, KPAT(r) + 4 * h);
        const size_t row = (size_t)(qw + KPAT(r) + 4 * h);
        Ob[row * DH + ql]      = o0[r] * ir;
        Ob[row * DH + 32 + ql] = o1[r] * ir;
    }
}

__global__ __launch_bounds__(256, 2) void attn_fwd(const float* __restrict__ Qg,
                                                   const short* __restrict__ Kimg,
                                                   const short* __restrict__ Vimg,
                                                   float* __restrict__ Og) {
    __shared__ __align__(16) short Ks[2][64 * 64];   // K tiles [k][d], swizzled, dbuf
    __shared__ __align__(16) short Vt[2][64 * 64];   // V tiles [d][k], swizzled, dbuf

    const int tid  = threadIdx.x;
    const int w    = tid >> 6;
    const int lane = tid & 63;
    const int h    = lane >> 5;      // half-wave (k-chunk selector)
    const int ql   = lane & 31;      // lane's q-col (S^T) / d-col (O)

    // paired q-blocks: A = p, B = 15-p. Per-wave active computes = 32/34 in
    // EVERY block (A-heavy rounds are few, B-only rounds thin) -> work uniform
    // by construction, independent of dispatch->CU mapping. 512 blocks = 2/CU.
    const int p   = blockIdx.x & 7;
    const int bh  = blockIdx.x >> 3;
    const int qblkA = p, qblkB = NQB - 1 - p;

    const float* Qb   = Qg + (size_t)bh * SEQ * DH;
    const short* kimg = Kimg + (size_t)bh * NTIL * 4096;
    const short* vimg = Vimg + (size_t)bh * NTIL * 4096;
    float*       Ob   = Og + (size_t)bh * SEQ * DH;

    const float SC = 0.125f * 1.44269504f;   // 1/sqrt(64) * log2(e)

    const int qwA = qblkA * QBLK + w * 32, qA = qwA + ql, kendA = qwA + 32;
    const int qwB = qblkB * QBLK + w * 32, qB = qwB + ql, kendB = qwB + 32;
    const int nt  = qblkB * 2 + 2;          // B needs the most tiles (p <= 7)

    STAGE(0, 0);                      // tile 0 in flight; Q conversion hides it

    bf16x8 qbA[4], qbB[4];
    load_qfrags(Qb, qA, h, SC, qbA);
    load_qfrags(Qb, qB, h, SC, qbB);

    f32x16 oA0, oA1, oB0, oB1;
    #pragma unroll
    for (int i = 0; i < 16; ++i) { oA0[i]=0.f; oA1[i]=0.f; oB0[i]=0.f; oB1[i]=0.f; }
    float mA = -1e30f, lA = 0.f, mB = -1e30f, lB = 0.f;

    __syncthreads();                  // buf0 ready (vmcnt drained at barrier)

    for (int t = 0; t < nt; ++t) {
        const int kb  = t * KBLK;
        const int cur = t & 1;
        if (t + 1 < nt) STAGE(cur ^ 1, t + 1);   // issue early: hides under compute

        // A and B chains are independent -> compiler interleaves MFMA/VALU
        tile_compute(&Ks[cur][0], &Vt[cur][0], kb, kendA, qwA, qA, h, ql,
                     qbA, oA0, oA1, mA, lA);
        tile_compute(&Ks[cur][0], &Vt[cur][0], kb, kendB, qwB, qB, h, ql,
                     qbB, oB0, oB1, mB, lB);

        __syncthreads();   // drains vmcnt: next tile ready; buf cur free for t+2
    }

    epilogue_store(Ob, qwA, h, ql, oA0, oA1, lA);
    epilogue_store(Ob, qwB, h, ql, oB0, oB1, lB);
}

// ================= fallback (reg-staged, used if ws too small) =================
#define LOAD_STAGE(kb_) do {                                               \
    const float* ksrc = Kb + (size_t)((kb_) + skr) * DH + sd0;             \
    kr0 = *reinterpret_cast<const float4*>(ksrc);                          \
    kr1 = *reinterpret_cast<const float4*>(ksrc + 4);                      \
    kr2 = *reinterpret_cast<const float4*>(ksrc + 8);                      \
    kr3 = *reinterpret_cast<const float4*>(ksrc + 12);                     \
    const float* vsrc = Vb + (size_t)((kb_) + svk) * DH + svd0;            \
    vr0 = *reinterpret_cast<const float4*>(vsrc);                          \
    vr1 = *reinterpret_cast<const float4*>(vsrc + 4);                      \
    vr2 = *reinterpret_cast<const float4*>(vsrc + 8);                      \
    vr3 = *reinterpret_cast<const float4*>(vsrc + 12);                     \
} while (0)

#define CVT_WRITE(b_) do {                                                 \
    V4U u0, u1;                                                            \
    u0.w[0] = cvtpk(kr0.x, kr0.y); u0.w[1] = cvtpk(kr0.z, kr0.w);          \
    u0.w[2] = cvtpk(kr1.x, kr1.y); u0.w[3] = cvtpk(kr1.z, kr1.w);          \
    u1.w[0] = cvtpk(kr2.x, kr2.y); u1.w[1] = cvtpk(kr2.z, kr2.w);          \
    u1.w[2] = cvtpk(kr3.x, kr3.y); u1.w[3] = cvtpk(kr3.z, kr3.w);          \
    *reinterpret_cast<bf16x8*>(&Ks[b_][swz(skr, sd0)])     = u0.v;         \
    *reinterpret_cast<bf16x8*>(&Ks[b_][swz(skr, sd0 + 8)]) = u1.v;         \
    const float vv[16] = {vr0.x,vr0.y,vr0.z,vr0.w, vr1.x,vr1.y,vr1.z,vr1.w,\
                          vr2.x,vr2.y,vr2.z,vr2.w, vr3.x,vr3.y,vr3.z,vr3.w};\
    _Pragma("unroll")                                                      \
    for (int i_ = 0; i_ < 16; ++i_)                                        \
        Vt[b_][swz(svd0 + i_, svk)] = bfbits(vv[i_]);                      \
} while (0)

__global__ __launch_bounds__(256) void attn_fwd_fb(const float* __restrict__ Qg,
                                                   const float* __restrict__ Kg,
                                                   const float* __restrict__ Vg,
                                                   float* __restrict__ Og) {
    __shared__ __align__(16) short Ks[2][64 * 64];
    __shared__ __align__(16) short Vt[2][64 * 64];

    const int tid  = threadIdx.x;
    const int w    = tid >> 6;
    const int lane = tid & 63;
    const int h    = lane >> 5;
    const int ql   = lane & 31;

    const int j    = blockIdx.x & (NQB - 1);
    const int bh   = blockIdx.x / NQB;
    const int qblk = ((bh >> 4) & 1) ? (NQB - 1 - j) : j;
    const int q0   = qblk * QBLK;
    const int qw   = q0 + w * 32;
    const int q    = qw + ql;

    const float* Qb = Qg + (size_t)bh * SEQ * DH;
    const float* Kb = Kg + (size_t)bh * SEQ * DH;
    const float* Vb = Vg + (size_t)bh * SEQ * DH;
    float*       Ob = Og + (size_t)bh * SEQ * DH;

    const float SC = 0.125f * 1.44269504f;

    const int skr  = tid >> 2;
    const int sd0  = (tid & 3) * 16;
    const int svk  = tid & 63;
    const int svd0 = (tid >> 6) * 16;

    float4 kr0, kr1, kr2, kr3, vr0, vr1, vr2, vr3;
    LOAD_STAGE(0);

    bf16x8 qb[4];
    load_qfrags(Qb, q, h, SC, qb);

    f32x16 o0, o1;
    #pragma unroll
    for (int i = 0; i < 16; ++i) { o0[i] = 0.f; o1[i] = 0.f; }
    float m = -1e30f, lsum = 0.f;

    CVT_WRITE(0);
    __syncthreads();

    const int kend = qw + 32;
    const int nt   = (q0 + QBLK) / KBLK;

    for (int t = 0; t < nt; ++t) {
        const int kb  = t * KBLK;
        const int cur = t & 1;
        if (t + 1 < nt) LOAD_STAGE(kb + KBLK);

        tile_compute(&Ks[cur][0], &Vt[cur][0], kb, kend, qw, q, h, ql,
                     qb, o0, o1, m, lsum);

        if (t + 1 < nt) CVT_WRITE(cur ^ 1);
        __syncthreads();
    }

    epilogue_store(Ob, qw, h, ql, o0, o1, lsum);
}

extern "C" void kernel_launch(void* const* d_in, const int* in_sizes, int n_in,
                              void* d_out, int out_size, void* d_ws, size_t ws_size,
                              hipStream_t stream) {
    const float* Q = (const float*)d_in[0];
    const float* K = (const float*)d_in[1];
    const float* V = (const float*)d_in[2];
    // d_in[3] causal mask: synthesized in-kernel, not read.
    float* O = (float*)d_out;

    if (ws_size >= WS_NEEDED) {
        short* Kimg = (short*)d_ws;
        short* Vimg = Kimg + (size_t)64 * NTIL * 4096;
        prep_kv<<<dim3(64 * NTIL), 256, 0, stream>>>(K, V, Kimg, Vimg);
        attn_fwd<<<dim3(64 * (NQB / 2)), 256, 0, stream>>>(Q, Kimg, Vimg, O);
    } else {
        attn_fwd_fb<<<dim3(64 * NQB), 256, 0, stream>>>(Q, K, V, O);
    }
}